// Round 9
// baseline (277.021 us; speedup 1.0000x reference)
//
#include <hip/hip_runtime.h>

// 2-layer GCN, CSR-gather formulation, v9 (= v7 structure + v8 pre-scale + nt-CSR).
//   Â = D^{-1/2}(A+I)D^{-1/2},  out = Â(relu(Â z W1 + b1))W2 + b2
// layer1: t1 = Â z (64-wide), h = relu(t1@W1+b1); layer2: hh = h@W2, out = Â hh + b2.
// v6: CSR build via two-level LDS counting sort by dst — zero global atomics.
// v7: bf16 gather operand, full 128B row per request (line-service-count bound).
// v9: operand pre-scaled by dinv (wscale pass deleted); CSR streamed with
// non-temporal loads so L2 is reserved for the gather operand; matmuls do
// 2 rows/thread to halve LDS weight traffic.

#define NPB 128   // nodes per fine bucket (dst & 127 is the in-bucket id)
#define CH  4096  // edges per chunk block in hist/scatter passes

__device__ __forceinline__ float4 ld4(const float* p) {
    return *reinterpret_cast<const float4*>(p);
}

// round-to-nearest-even f32 -> bf16 (as ushort in low bits)
__device__ __forceinline__ unsigned bfr(float f) {
    unsigned u = __float_as_uint(f);
    return (u + 0x7FFFu + ((u >> 16) & 1u)) >> 16;
}
// unpack 4 bf16 (uint2) -> 4 f32
__device__ __forceinline__ void bf4(uint2 v, float& f0, float& f1, float& f2, float& f3) {
    f0 = __uint_as_float(v.x << 16);
    f1 = __uint_as_float(v.x & 0xFFFF0000u);
    f2 = __uint_as_float(v.y << 16);
    f3 = __uint_as_float(v.y & 0xFFFF0000u);
}

// ---- K1: coarse histogram per chunk (LDS), bucket-major out: hist[b*G1+g] ----
__global__ __launch_bounds__(256) void hist_kernel(const int* __restrict__ dst,
                                                   int* __restrict__ hist,
                                                   int E, int G1, int NBKT) {
    __shared__ int lh[512];
    for (int i = threadIdx.x; i < NBKT; i += 256) lh[i] = 0;
    __syncthreads();
    int g = blockIdx.x;
    int beg = g * CH, end = min(beg + CH, E);
    for (int j = beg + (int)threadIdx.x; j < end; j += 256)
        atomicAdd(&lh[dst[j] / NPB], 1);
    __syncthreads();
    for (int i = threadIdx.x; i < NBKT; i += 256) hist[(size_t)i * G1 + g] = lh[i];
}

// ---- K2a: per-bucket exclusive scan across chunks (in place); btot[b] = total ----
__global__ __launch_bounds__(64) void bscan_kernel(int* __restrict__ hist,
                                                   int* __restrict__ btot, int G1) {
    int b = blockIdx.x;
    int* row = hist + (size_t)b * G1;
    int lane = threadIdx.x;
    int carry = 0;
    for (int g0 = 0; g0 < G1; g0 += 64) {
        int g = g0 + lane;
        int v = (g < G1) ? row[g] : 0;
        int incl = v;
#pragma unroll
        for (int off = 1; off < 64; off <<= 1) {
            int u = __shfl_up(incl, off, 64);
            if (lane >= off) incl += u;
        }
        if (g < G1) row[g] = carry + incl - v;
        carry += __shfl(incl, 63, 64);
    }
    if (lane == 0) btot[b] = carry;
}

// ---- K2b: exclusive scan of bucket totals -> bucket bases (NBKT <= 512) ----
__global__ __launch_bounds__(512) void tscan_kernel(const int* __restrict__ btot,
                                                    int* __restrict__ bbase, int NBKT) {
    __shared__ int ws[8];
    int t = threadIdx.x;
    int v = (t < NBKT) ? btot[t] : 0;
    int lane = t & 63, wid = t >> 6;
    int incl = v;
#pragma unroll
    for (int off = 1; off < 64; off <<= 1) {
        int u = __shfl_up(incl, off, 64);
        if (lane >= off) incl += u;
    }
    if (lane == 63) ws[wid] = incl;
    __syncthreads();
    int woff = 0;
#pragma unroll
    for (int w = 0; w < 8; ++w) if (w < wid) woff += ws[w];
    if (t < NBKT) bbase[t] = woff + incl - v;
}

// ---- K3: scatter edges into bucket-grouped tmp via LDS cursors ----
__global__ __launch_bounds__(256) void scatter_kernel(const int* __restrict__ src,
                                                      const int* __restrict__ dst,
                                                      const float* __restrict__ ew,
                                                      const int* __restrict__ hist,
                                                      const int* __restrict__ bbase,
                                                      int2* __restrict__ tmp,
                                                      int E, int G1, int NBKT) {
    __shared__ int cursor[512];
    int g = blockIdx.x;
    for (int i = threadIdx.x; i < NBKT; i += 256)
        cursor[i] = bbase[i] + hist[(size_t)i * G1 + g];
    __syncthreads();
    int beg = g * CH, end = min(beg + CH, E);
    for (int j = beg + (int)threadIdx.x; j < end; j += 256) {
        int d = dst[j];
        int b = d / NPB;
        int pos = atomicAdd(&cursor[b], 1);
        tmp[pos] = make_int2(((d & (NPB - 1)) << 24) | src[j], __float_as_int(ew[j]));
    }
}

// ---- K4: per-bucket finalize: exact rowptr, dinv, final CSR {src, ew} ----
__global__ __launch_bounds__(256) void finalize_kernel(const int2* __restrict__ tmp,
                                                       const int* __restrict__ bbase,
                                                       const int* __restrict__ btot,
                                                       int* __restrict__ rowptr,
                                                       float* __restrict__ dinv,
                                                       int2* __restrict__ csr,
                                                       int n, int E) {
    __shared__ unsigned int hist[NPB];
    __shared__ int wsum_[2];
    int b = blockIdx.x;
    int base = bbase[b];
    int cnt  = btot[b];
    int tid  = threadIdx.x;
    if (tid < NPB) hist[tid] = 0;
    __syncthreads();
    for (int j = tid; j < cnt; j += 256) {
        int2 t = tmp[base + j];
        unsigned dlow = ((unsigned)t.x) >> 24;
        unsigned wfix = (unsigned)(__int_as_float(t.y) * 16384.0f);
        atomicAdd(&hist[dlow], (1u << 24) | wfix);
    }
    __syncthreads();
    int c = 0, incl = 0;
    unsigned pk = 0;
    if (tid < NPB) {
        pk = hist[tid];
        c = (int)(pk >> 24);
        incl = c;
#pragma unroll
        for (int off = 1; off < 64; off <<= 1) {
            int u = __shfl_up(incl, off, 64);
            if ((tid & 63) >= off) incl += u;
        }
        if ((tid & 63) == 63) wsum_[tid >> 6] = incl;
    }
    __syncthreads();
    if (tid < NPB) {
        int woff = (tid >= 64) ? wsum_[0] : 0;
        int excl = woff + incl - c;
        int node = b * NPB + tid;
        if (node < n) {
            rowptr[node] = base + excl;
            float wdeg = (float)(pk & 0xFFFFFFu) * (1.0f / 16384.0f);
            dinv[node] = rsqrtf(wdeg + 1.0f);
        }
        hist[tid] = (unsigned)excl;
    }
    if (b == 0 && tid == 0) rowptr[n] = E;
    __syncthreads();
    for (int j = tid; j < cnt; j += 256) {
        int2 t = tmp[base + j];
        unsigned dlow = ((unsigned)t.x) >> 24;
        int srcv = t.x & 0xFFFFFF;
        int lr = (int)atomicAdd(&hist[dlow], 1u);
        csr[base + lr] = make_int2(srcv, t.y);
    }
}

// ---- K5: zs = bf16(dinv[r] * z[r]), contiguous [n][16 uint2] (128B rows) ----
__global__ __launch_bounds__(256) void convs_kernel(const float* __restrict__ z,
                                                    const float* __restrict__ dinv,
                                                    uint2* __restrict__ zs, int n) {
    int t = blockIdx.x * 256 + threadIdx.x;
    if (t >= n * 16) return;
    int r = t >> 4, k = t & 15;
    float dv = dinv[r];
    float4 f = ld4(z + (size_t)r * 64 + k * 4);
    zs[t] = make_uint2(bfr(dv * f.x) | (bfr(dv * f.y) << 16),
                       bfr(dv * f.z) | (bfr(dv * f.w) << 16));
}

// ---- gather-aggregate (F=64, bf16 pre-scaled operand): one wave per dst row ----
// Lane l: eg = l>>4 (edge subgroup), fq = l&15 (feature uint2 = 4 bf16).
// out[row] = (BIAS? b : 0) + dv * ( sum_j ew_j * Hp[src_j] + Hp[row] )
template<bool BIAS>
__global__ __launch_bounds__(256) void gaggb_kernel(const int* __restrict__ rowptr,
                                                    const long long* __restrict__ csr,
                                                    const float* __restrict__ dinv,
                                                    const uint2* __restrict__ Hp,
                                                    const float* __restrict__ b,
                                                    float* __restrict__ out, int n) {
    int row  = (blockIdx.x * 256 + threadIdx.x) >> 6;
    int lane = threadIdx.x & 63;
    if (row >= n) return;
    int eg = lane >> 4, fq = lane & 15;
    int beg = rowptr[row], end = rowptr[row + 1];
    float dv = dinv[row];

    float ax = 0.f, ay = 0.f, az = 0.f, aw = 0.f;
    float f0, f1, f2, f3;
    int j = beg;
    for (; j + 16 <= end; j += 16) {
        long long e0 = __builtin_nontemporal_load(csr + j + eg);
        long long e1 = __builtin_nontemporal_load(csr + j + eg + 4);
        long long e2 = __builtin_nontemporal_load(csr + j + eg + 8);
        long long e3 = __builtin_nontemporal_load(csr + j + eg + 12);
        uint2 v0 = Hp[(size_t)(unsigned)(e0 & 0xFFFFFF) * 16 + fq];
        uint2 v1 = Hp[(size_t)(unsigned)(e1 & 0xFFFFFF) * 16 + fq];
        uint2 v2 = Hp[(size_t)(unsigned)(e2 & 0xFFFFFF) * 16 + fq];
        uint2 v3 = Hp[(size_t)(unsigned)(e3 & 0xFFFFFF) * 16 + fq];
        float w0 = __int_as_float((int)(e0 >> 32));
        float w1 = __int_as_float((int)(e1 >> 32));
        float w2 = __int_as_float((int)(e2 >> 32));
        float w3 = __int_as_float((int)(e3 >> 32));
        bf4(v0, f0, f1, f2, f3);
        ax += w0 * f0; ay += w0 * f1; az += w0 * f2; aw += w0 * f3;
        bf4(v1, f0, f1, f2, f3);
        ax += w1 * f0; ay += w1 * f1; az += w1 * f2; aw += w1 * f3;
        bf4(v2, f0, f1, f2, f3);
        ax += w2 * f0; ay += w2 * f1; az += w2 * f2; aw += w2 * f3;
        bf4(v3, f0, f1, f2, f3);
        ax += w3 * f0; ay += w3 * f1; az += w3 * f2; aw += w3 * f3;
    }
    for (; j + 4 <= end; j += 4) {
        long long e0 = __builtin_nontemporal_load(csr + j + eg);
        float w0 = __int_as_float((int)(e0 >> 32));
        uint2 v0 = Hp[(size_t)(unsigned)(e0 & 0xFFFFFF) * 16 + fq];
        bf4(v0, f0, f1, f2, f3);
        ax += w0 * f0; ay += w0 * f1; az += w0 * f2; aw += w0 * f3;
    }
    if (j < end) {
        int idx = j + eg;
        if (idx < end) {
            long long e0 = __builtin_nontemporal_load(csr + idx);
            float w0 = __int_as_float((int)(e0 >> 32));
            uint2 v0 = Hp[(size_t)(unsigned)(e0 & 0xFFFFFF) * 16 + fq];
            bf4(v0, f0, f1, f2, f3);
            ax += w0 * f0; ay += w0 * f1; az += w0 * f2; aw += w0 * f3;
        }
    }
    // combine the 4 edge subgroups (lane bits 4,5)
    ax += __shfl_xor(ax, 16, 64); ay += __shfl_xor(ay, 16, 64);
    az += __shfl_xor(az, 16, 64); aw += __shfl_xor(aw, 16, 64);
    ax += __shfl_xor(ax, 32, 64); ay += __shfl_xor(ay, 32, 64);
    az += __shfl_xor(az, 32, 64); aw += __shfl_xor(aw, 32, 64);

    if (eg == 0) {
        uint2 sv = Hp[(size_t)row * 16 + fq];   // self term (already dinv-scaled)
        float s0, s1, s2, s3;
        bf4(sv, s0, s1, s2, s3);
        float4 o;
        o.x = dv * (ax + s0);
        o.y = dv * (ay + s1);
        o.z = dv * (az + s2);
        o.w = dv * (aw + s3);
        if (BIAS) {
            float4 bb = ld4(b + fq * 4);
            o.x += bb.x; o.y += bb.y; o.z += bb.z; o.w += bb.w;
        }
        reinterpret_cast<float4*>(out)[(size_t)row * 16 + fq] = o;
    }
}

// ---- dense matmul, 2 rows/thread (reuse W reads): Y = (X@W)[+b][relu] ----
// OUTB: Y = bf16(dinv[r] * row) packed uint2, contiguous [n][FOUT/4].
template<int FIN, int FOUT, bool RELU, bool BIAS, bool OUTB>
__global__ __launch_bounds__(256) void matmulE_kernel(const float* __restrict__ X,
                                                      const float* __restrict__ W,
                                                      const float* __restrict__ b,
                                                      const float* __restrict__ dinv,
                                                      void* __restrict__ Y, int n) {
    constexpr int QPR  = FOUT / 4;      // threads per row (4 outputs each)
    constexpr int TRPB = 256 / QPR;     // thread-rows per block
    constexpr int RPB  = TRPB * 2;      // rows per block (2 rows per thread)
    __shared__ float Ws[FIN * FOUT];
    for (int i = threadIdx.x; i < FIN * FOUT / 4; i += 256)
        reinterpret_cast<float4*>(Ws)[i] = reinterpret_cast<const float4*>(W)[i];
    __syncthreads();

    int tr = threadIdx.x / QPR;
    int q  = threadIdx.x % QPR;
    int r0 = blockIdx.x * RPB + tr;
    int r1 = r0 + TRPB;
    if (r0 >= n) return;
    bool has1 = (r1 < n);
    const float* x0 = X + (size_t)r0 * FIN;
    const float* x1 = X + (size_t)(has1 ? r1 : r0) * FIN;

    float ax0 = 0.f, ay0 = 0.f, az0 = 0.f, aw0 = 0.f;
    float ax1 = 0.f, ay1 = 0.f, az1 = 0.f, aw1 = 0.f;
#pragma unroll
    for (int k = 0; k < FIN; k += 4) {
        float4 a0 = ld4(x0 + k);
        float4 a1 = ld4(x1 + k);
        float4 w0 = ld4(&Ws[(k + 0) * FOUT + q * 4]);
        float4 w1 = ld4(&Ws[(k + 1) * FOUT + q * 4]);
        float4 w2 = ld4(&Ws[(k + 2) * FOUT + q * 4]);
        float4 w3 = ld4(&Ws[(k + 3) * FOUT + q * 4]);
        ax0 += a0.x * w0.x + a0.y * w1.x + a0.z * w2.x + a0.w * w3.x;
        ay0 += a0.x * w0.y + a0.y * w1.y + a0.z * w2.y + a0.w * w3.y;
        az0 += a0.x * w0.z + a0.y * w1.z + a0.z * w2.z + a0.w * w3.z;
        aw0 += a0.x * w0.w + a0.y * w1.w + a0.z * w2.w + a0.w * w3.w;
        ax1 += a1.x * w0.x + a1.y * w1.x + a1.z * w2.x + a1.w * w3.x;
        ay1 += a1.x * w0.y + a1.y * w1.y + a1.z * w2.y + a1.w * w3.y;
        az1 += a1.x * w0.z + a1.y * w1.z + a1.z * w2.z + a1.w * w3.z;
        aw1 += a1.x * w0.w + a1.y * w1.w + a1.z * w2.w + a1.w * w3.w;
    }
#pragma unroll
    for (int rr = 0; rr < 2; ++rr) {
        int r = rr ? r1 : r0;
        if (rr && !has1) break;
        float4 o = rr ? make_float4(ax1, ay1, az1, aw1)
                      : make_float4(ax0, ay0, az0, aw0);
        if (BIAS) {
            float4 bb = ld4(b + q * 4);
            o.x += bb.x; o.y += bb.y; o.z += bb.z; o.w += bb.w;
        }
        if (RELU) {
            o.x = fmaxf(o.x, 0.f); o.y = fmaxf(o.y, 0.f);
            o.z = fmaxf(o.z, 0.f); o.w = fmaxf(o.w, 0.f);
        }
        if (OUTB) {
            float dvr = dinv[r];
            o.x *= dvr; o.y *= dvr; o.z *= dvr; o.w *= dvr;
            uint2 pv = make_uint2(bfr(o.x) | (bfr(o.y) << 16),
                                  bfr(o.z) | (bfr(o.w) << 16));
            reinterpret_cast<uint2*>(Y)[(size_t)r * QPR + q] = pv;
        } else {
            reinterpret_cast<float4*>(Y)[(size_t)r * QPR + q] = o;
        }
    }
}

extern "C" void kernel_launch(void* const* d_in, const int* in_sizes, int n_in,
                              void* d_out, int out_size, void* d_ws, size_t ws_size,
                              hipStream_t stream) {
    const float* z  = (const float*)d_in[0];
    const int*   ei = (const int*)d_in[1];
    const float* ea = (const float*)d_in[2];
    const float* W1 = (const float*)d_in[3];
    const float* b1 = (const float*)d_in[4];
    const float* W2 = (const float*)d_in[5];
    const float* b2 = (const float*)d_in[6];
    float* out = (float*)d_out;

    const int n = in_sizes[0] / 64;   // LAT = 64
    const int E = in_sizes[2];
    const int* src = ei;
    const int* dst = ei + E;
    const int NBKT = (n + NPB - 1) / NPB;   // 391 for n=50000 (<=512 required)
    const int G1   = (E + CH - 1) / CH;     // chunk blocks

    float* ws = (float*)d_ws;
    size_t p = 0;
    auto alloc = [&](size_t elems) { size_t o = p; p += (elems + 63) & ~63ull; return o; };
    float* dinv   = ws + alloc(n);
    int*   rowptr = (int*)(ws + alloc((size_t)n + 1));
    int*   btot   = (int*)(ws + alloc(NBKT));
    int*   bbase  = (int*)(ws + alloc(NBKT));
    int2*  csr    = (int2*)(ws + alloc((size_t)E * 2));
    float* t1     = ws + alloc((size_t)n * 64);            // Â z (f32), matmul1 input
    uint2* zs     = (uint2*)(ws + alloc((size_t)n * 32));  // bf16 pre-scaled operand
    // region X: tmp+hist (preprocessing) then h (layers) — tmp dead before h written
    float* X      = ws + alloc((size_t)n * 128);
    int2*  tmp    = (int2*)X;                       // E int2
    int*   hist   = (int*)(X + (size_t)E * 2);      // NBKT*G1 ints
    float* h      = X;
    (void)ws_size;

    // ---- preprocessing: counting sort by dst, zero global atomics ----
    hist_kernel<<<G1, 256, 0, stream>>>(dst, hist, E, G1, NBKT);
    bscan_kernel<<<NBKT, 64, 0, stream>>>(hist, btot, G1);
    tscan_kernel<<<1, 512, 0, stream>>>(btot, bbase, NBKT);
    scatter_kernel<<<G1, 256, 0, stream>>>(src, dst, ea, hist, bbase, tmp, E, G1, NBKT);
    finalize_kernel<<<NBKT, 256, 0, stream>>>(tmp, bbase, btot, rowptr, dinv, csr, n, E);
    convs_kernel<<<(n * 16 + 255) / 256, 256, 0, stream>>>(z, dinv, zs, n);

    const int gblocks = (n + 3) / 4;
    // ---- layer 1: t1 = Â z ; h = relu(t1 @ W1 + b1) ----
    gaggb_kernel<false><<<gblocks, 256, 0, stream>>>(rowptr, (const long long*)csr,
                                                     dinv, zs, nullptr, t1, n);
    matmulE_kernel<64, 128, true, true, false><<<(n + 15) / 16, 256, 0, stream>>>(
        t1, W1, b1, nullptr, h, n);

    // ---- layer 2: hs = bf16(dinv*(h @ W2)) (reuses zs) ; out = gather + b2 ----
    matmulE_kernel<128, 64, false, false, true><<<(n + 31) / 32, 256, 0, stream>>>(
        h, W2, nullptr, dinv, zs, n);
    gaggb_kernel<true><<<gblocks, 256, 0, stream>>>(rowptr, (const long long*)csr,
                                                    dinv, zs, b2, out, n);
}

// Round 10
// 193.907 us; speedup vs baseline: 1.4286x; 1.4286x over previous
//
#include <hip/hip_runtime.h>

// 2-layer GCN, CSR-gather formulation, v10 (= v7 structure + pre-scale + nt-CSR;
// matmul reverted to single-row/thread after v9's VGPR=256 occupancy cliff).
//   Â = D^{-1/2}(A+I)D^{-1/2},  out = Â(relu(Â z W1 + b1))W2 + b2
// layer1: t1 = Â z (64-wide), h = relu(t1@W1+b1); layer2: hh = h@W2, out = Â hh + b2.
// v6: CSR build via two-level LDS counting sort by dst — zero global atomics.
// v7: bf16 gather operand, full 128B row per request (line-service-count bound).
// v9-kept: operand pre-scaled by dinv (wscale deleted); nt loads for CSR stream.
// v10: matmul single row/thread (2-row variant hit 256 VGPR -> 9.8% occupancy).

#define NPB 128   // nodes per fine bucket (dst & 127 is the in-bucket id)
#define CH  4096  // edges per chunk block in hist/scatter passes

__device__ __forceinline__ float4 ld4(const float* p) {
    return *reinterpret_cast<const float4*>(p);
}

// round-to-nearest-even f32 -> bf16 (as ushort in low bits)
__device__ __forceinline__ unsigned bfr(float f) {
    unsigned u = __float_as_uint(f);
    return (u + 0x7FFFu + ((u >> 16) & 1u)) >> 16;
}
// unpack 4 bf16 (uint2) -> 4 f32
__device__ __forceinline__ void bf4(uint2 v, float& f0, float& f1, float& f2, float& f3) {
    f0 = __uint_as_float(v.x << 16);
    f1 = __uint_as_float(v.x & 0xFFFF0000u);
    f2 = __uint_as_float(v.y << 16);
    f3 = __uint_as_float(v.y & 0xFFFF0000u);
}

// ---- K1: coarse histogram per chunk (LDS), bucket-major out: hist[b*G1+g] ----
__global__ __launch_bounds__(256) void hist_kernel(const int* __restrict__ dst,
                                                   int* __restrict__ hist,
                                                   int E, int G1, int NBKT) {
    __shared__ int lh[512];
    for (int i = threadIdx.x; i < NBKT; i += 256) lh[i] = 0;
    __syncthreads();
    int g = blockIdx.x;
    int beg = g * CH, end = min(beg + CH, E);
    for (int j = beg + (int)threadIdx.x; j < end; j += 256)
        atomicAdd(&lh[dst[j] / NPB], 1);
    __syncthreads();
    for (int i = threadIdx.x; i < NBKT; i += 256) hist[(size_t)i * G1 + g] = lh[i];
}

// ---- K2a: per-bucket exclusive scan across chunks (in place); btot[b] = total ----
__global__ __launch_bounds__(64) void bscan_kernel(int* __restrict__ hist,
                                                   int* __restrict__ btot, int G1) {
    int b = blockIdx.x;
    int* row = hist + (size_t)b * G1;
    int lane = threadIdx.x;
    int carry = 0;
    for (int g0 = 0; g0 < G1; g0 += 64) {
        int g = g0 + lane;
        int v = (g < G1) ? row[g] : 0;
        int incl = v;
#pragma unroll
        for (int off = 1; off < 64; off <<= 1) {
            int u = __shfl_up(incl, off, 64);
            if (lane >= off) incl += u;
        }
        if (g < G1) row[g] = carry + incl - v;
        carry += __shfl(incl, 63, 64);
    }
    if (lane == 0) btot[b] = carry;
}

// ---- K2b: exclusive scan of bucket totals -> bucket bases (NBKT <= 512) ----
__global__ __launch_bounds__(512) void tscan_kernel(const int* __restrict__ btot,
                                                    int* __restrict__ bbase, int NBKT) {
    __shared__ int ws[8];
    int t = threadIdx.x;
    int v = (t < NBKT) ? btot[t] : 0;
    int lane = t & 63, wid = t >> 6;
    int incl = v;
#pragma unroll
    for (int off = 1; off < 64; off <<= 1) {
        int u = __shfl_up(incl, off, 64);
        if (lane >= off) incl += u;
    }
    if (lane == 63) ws[wid] = incl;
    __syncthreads();
    int woff = 0;
#pragma unroll
    for (int w = 0; w < 8; ++w) if (w < wid) woff += ws[w];
    if (t < NBKT) bbase[t] = woff + incl - v;
}

// ---- K3: scatter edges into bucket-grouped tmp via LDS cursors ----
__global__ __launch_bounds__(256) void scatter_kernel(const int* __restrict__ src,
                                                      const int* __restrict__ dst,
                                                      const float* __restrict__ ew,
                                                      const int* __restrict__ hist,
                                                      const int* __restrict__ bbase,
                                                      int2* __restrict__ tmp,
                                                      int E, int G1, int NBKT) {
    __shared__ int cursor[512];
    int g = blockIdx.x;
    for (int i = threadIdx.x; i < NBKT; i += 256)
        cursor[i] = bbase[i] + hist[(size_t)i * G1 + g];
    __syncthreads();
    int beg = g * CH, end = min(beg + CH, E);
    for (int j = beg + (int)threadIdx.x; j < end; j += 256) {
        int d = dst[j];
        int b = d / NPB;
        int pos = atomicAdd(&cursor[b], 1);
        tmp[pos] = make_int2(((d & (NPB - 1)) << 24) | src[j], __float_as_int(ew[j]));
    }
}

// ---- K4: per-bucket finalize: exact rowptr, dinv, final CSR {src, ew} ----
__global__ __launch_bounds__(256) void finalize_kernel(const int2* __restrict__ tmp,
                                                       const int* __restrict__ bbase,
                                                       const int* __restrict__ btot,
                                                       int* __restrict__ rowptr,
                                                       float* __restrict__ dinv,
                                                       int2* __restrict__ csr,
                                                       int n, int E) {
    __shared__ unsigned int hist[NPB];
    __shared__ int wsum_[2];
    int b = blockIdx.x;
    int base = bbase[b];
    int cnt  = btot[b];
    int tid  = threadIdx.x;
    if (tid < NPB) hist[tid] = 0;
    __syncthreads();
    for (int j = tid; j < cnt; j += 256) {
        int2 t = tmp[base + j];
        unsigned dlow = ((unsigned)t.x) >> 24;
        unsigned wfix = (unsigned)(__int_as_float(t.y) * 16384.0f);
        atomicAdd(&hist[dlow], (1u << 24) | wfix);
    }
    __syncthreads();
    int c = 0, incl = 0;
    unsigned pk = 0;
    if (tid < NPB) {
        pk = hist[tid];
        c = (int)(pk >> 24);
        incl = c;
#pragma unroll
        for (int off = 1; off < 64; off <<= 1) {
            int u = __shfl_up(incl, off, 64);
            if ((tid & 63) >= off) incl += u;
        }
        if ((tid & 63) == 63) wsum_[tid >> 6] = incl;
    }
    __syncthreads();
    if (tid < NPB) {
        int woff = (tid >= 64) ? wsum_[0] : 0;
        int excl = woff + incl - c;
        int node = b * NPB + tid;
        if (node < n) {
            rowptr[node] = base + excl;
            float wdeg = (float)(pk & 0xFFFFFFu) * (1.0f / 16384.0f);
            dinv[node] = rsqrtf(wdeg + 1.0f);
        }
        hist[tid] = (unsigned)excl;
    }
    if (b == 0 && tid == 0) rowptr[n] = E;
    __syncthreads();
    for (int j = tid; j < cnt; j += 256) {
        int2 t = tmp[base + j];
        unsigned dlow = ((unsigned)t.x) >> 24;
        int srcv = t.x & 0xFFFFFF;
        int lr = (int)atomicAdd(&hist[dlow], 1u);
        csr[base + lr] = make_int2(srcv, t.y);
    }
}

// ---- K5: zs = bf16(dinv[r] * z[r]), contiguous [n][16 uint2] (128B rows) ----
__global__ __launch_bounds__(256) void convs_kernel(const float* __restrict__ z,
                                                    const float* __restrict__ dinv,
                                                    uint2* __restrict__ zs, int n) {
    int t = blockIdx.x * 256 + threadIdx.x;
    if (t >= n * 16) return;
    int r = t >> 4, k = t & 15;
    float dv = dinv[r];
    float4 f = ld4(z + (size_t)r * 64 + k * 4);
    zs[t] = make_uint2(bfr(dv * f.x) | (bfr(dv * f.y) << 16),
                       bfr(dv * f.z) | (bfr(dv * f.w) << 16));
}

// ---- gather-aggregate (F=64, bf16 pre-scaled operand): one wave per dst row ----
// Lane l: eg = l>>4 (edge subgroup), fq = l&15 (feature uint2 = 4 bf16).
// out[row] = (BIAS? b : 0) + dv * ( sum_j ew_j * Hp[src_j] + Hp[row] )
template<bool BIAS>
__global__ __launch_bounds__(256) void gaggb_kernel(const int* __restrict__ rowptr,
                                                    const long long* __restrict__ csr,
                                                    const float* __restrict__ dinv,
                                                    const uint2* __restrict__ Hp,
                                                    const float* __restrict__ b,
                                                    float* __restrict__ out, int n) {
    int row  = (blockIdx.x * 256 + threadIdx.x) >> 6;
    int lane = threadIdx.x & 63;
    if (row >= n) return;
    int eg = lane >> 4, fq = lane & 15;
    int beg = rowptr[row], end = rowptr[row + 1];
    float dv = dinv[row];

    float ax = 0.f, ay = 0.f, az = 0.f, aw = 0.f;
    float f0, f1, f2, f3;
    int j = beg;
    for (; j + 16 <= end; j += 16) {
        long long e0 = __builtin_nontemporal_load(csr + j + eg);
        long long e1 = __builtin_nontemporal_load(csr + j + eg + 4);
        long long e2 = __builtin_nontemporal_load(csr + j + eg + 8);
        long long e3 = __builtin_nontemporal_load(csr + j + eg + 12);
        uint2 v0 = Hp[(size_t)(unsigned)(e0 & 0xFFFFFF) * 16 + fq];
        uint2 v1 = Hp[(size_t)(unsigned)(e1 & 0xFFFFFF) * 16 + fq];
        uint2 v2 = Hp[(size_t)(unsigned)(e2 & 0xFFFFFF) * 16 + fq];
        uint2 v3 = Hp[(size_t)(unsigned)(e3 & 0xFFFFFF) * 16 + fq];
        float w0 = __int_as_float((int)(e0 >> 32));
        float w1 = __int_as_float((int)(e1 >> 32));
        float w2 = __int_as_float((int)(e2 >> 32));
        float w3 = __int_as_float((int)(e3 >> 32));
        bf4(v0, f0, f1, f2, f3);
        ax += w0 * f0; ay += w0 * f1; az += w0 * f2; aw += w0 * f3;
        bf4(v1, f0, f1, f2, f3);
        ax += w1 * f0; ay += w1 * f1; az += w1 * f2; aw += w1 * f3;
        bf4(v2, f0, f1, f2, f3);
        ax += w2 * f0; ay += w2 * f1; az += w2 * f2; aw += w2 * f3;
        bf4(v3, f0, f1, f2, f3);
        ax += w3 * f0; ay += w3 * f1; az += w3 * f2; aw += w3 * f3;
    }
    for (; j + 4 <= end; j += 4) {
        long long e0 = __builtin_nontemporal_load(csr + j + eg);
        float w0 = __int_as_float((int)(e0 >> 32));
        uint2 v0 = Hp[(size_t)(unsigned)(e0 & 0xFFFFFF) * 16 + fq];
        bf4(v0, f0, f1, f2, f3);
        ax += w0 * f0; ay += w0 * f1; az += w0 * f2; aw += w0 * f3;
    }
    if (j < end) {
        int idx = j + eg;
        if (idx < end) {
            long long e0 = __builtin_nontemporal_load(csr + idx);
            float w0 = __int_as_float((int)(e0 >> 32));
            uint2 v0 = Hp[(size_t)(unsigned)(e0 & 0xFFFFFF) * 16 + fq];
            bf4(v0, f0, f1, f2, f3);
            ax += w0 * f0; ay += w0 * f1; az += w0 * f2; aw += w0 * f3;
        }
    }
    // combine the 4 edge subgroups (lane bits 4,5)
    ax += __shfl_xor(ax, 16, 64); ay += __shfl_xor(ay, 16, 64);
    az += __shfl_xor(az, 16, 64); aw += __shfl_xor(aw, 16, 64);
    ax += __shfl_xor(ax, 32, 64); ay += __shfl_xor(ay, 32, 64);
    az += __shfl_xor(az, 32, 64); aw += __shfl_xor(aw, 32, 64);

    if (eg == 0) {
        uint2 sv = Hp[(size_t)row * 16 + fq];   // self term (already dinv-scaled)
        float s0, s1, s2, s3;
        bf4(sv, s0, s1, s2, s3);
        float4 o;
        o.x = dv * (ax + s0);
        o.y = dv * (ay + s1);
        o.z = dv * (az + s2);
        o.w = dv * (aw + s3);
        if (BIAS) {
            float4 bb = ld4(b + fq * 4);
            o.x += bb.x; o.y += bb.y; o.z += bb.z; o.w += bb.w;
        }
        reinterpret_cast<float4*>(out)[(size_t)row * 16 + fq] = o;
    }
}

// ---- dense matmul (single row/thread): Y = (X @ W) [+b] [relu] ----
// OUTB: Y = bf16(dinv[r] * row) packed uint2, contiguous [n][FOUT/4].
template<int FIN, int FOUT, bool RELU, bool BIAS, bool OUTB>
__global__ __launch_bounds__(256) void matmulE_kernel(const float* __restrict__ X,
                                                      const float* __restrict__ W,
                                                      const float* __restrict__ b,
                                                      const float* __restrict__ dinv,
                                                      void* __restrict__ Y, int n) {
    constexpr int QPR = FOUT / 4;     // threads per row (4 outputs each)
    constexpr int RPB = 256 / QPR;    // rows per block
    __shared__ float Ws[FIN * FOUT];
    for (int i = threadIdx.x; i < FIN * FOUT / 4; i += 256)
        reinterpret_cast<float4*>(Ws)[i] = reinterpret_cast<const float4*>(W)[i];
    __syncthreads();

    int r = blockIdx.x * RPB + threadIdx.x / QPR;
    int q = threadIdx.x % QPR;
    if (r >= n) return;
    const float* xr = X + (size_t)r * FIN;

    float ax = 0.f, ay = 0.f, az = 0.f, aw = 0.f;
#pragma unroll
    for (int k = 0; k < FIN; k += 4) {
        float4 a = ld4(xr + k);
        float4 w0 = ld4(&Ws[(k + 0) * FOUT + q * 4]);
        float4 w1 = ld4(&Ws[(k + 1) * FOUT + q * 4]);
        float4 w2 = ld4(&Ws[(k + 2) * FOUT + q * 4]);
        float4 w3 = ld4(&Ws[(k + 3) * FOUT + q * 4]);
        ax += a.x * w0.x + a.y * w1.x + a.z * w2.x + a.w * w3.x;
        ay += a.x * w0.y + a.y * w1.y + a.z * w2.y + a.w * w3.y;
        az += a.x * w0.z + a.y * w1.z + a.z * w2.z + a.w * w3.z;
        aw += a.x * w0.w + a.y * w1.w + a.z * w2.w + a.w * w3.w;
    }
    float4 o = make_float4(ax, ay, az, aw);
    if (BIAS) {
        float4 bb = ld4(b + q * 4);
        o.x += bb.x; o.y += bb.y; o.z += bb.z; o.w += bb.w;
    }
    if (RELU) {
        o.x = fmaxf(o.x, 0.f); o.y = fmaxf(o.y, 0.f);
        o.z = fmaxf(o.z, 0.f); o.w = fmaxf(o.w, 0.f);
    }
    if (OUTB) {
        float dvr = dinv[r];
        o.x *= dvr; o.y *= dvr; o.z *= dvr; o.w *= dvr;
        uint2 pv = make_uint2(bfr(o.x) | (bfr(o.y) << 16),
                              bfr(o.z) | (bfr(o.w) << 16));
        reinterpret_cast<uint2*>(Y)[(size_t)r * QPR + q] = pv;
    } else {
        reinterpret_cast<float4*>(Y)[(size_t)r * QPR + q] = o;
    }
}

extern "C" void kernel_launch(void* const* d_in, const int* in_sizes, int n_in,
                              void* d_out, int out_size, void* d_ws, size_t ws_size,
                              hipStream_t stream) {
    const float* z  = (const float*)d_in[0];
    const int*   ei = (const int*)d_in[1];
    const float* ea = (const float*)d_in[2];
    const float* W1 = (const float*)d_in[3];
    const float* b1 = (const float*)d_in[4];
    const float* W2 = (const float*)d_in[5];
    const float* b2 = (const float*)d_in[6];
    float* out = (float*)d_out;

    const int n = in_sizes[0] / 64;   // LAT = 64
    const int E = in_sizes[2];
    const int* src = ei;
    const int* dst = ei + E;
    const int NBKT = (n + NPB - 1) / NPB;   // 391 for n=50000 (<=512 required)
    const int G1   = (E + CH - 1) / CH;     // chunk blocks

    float* ws = (float*)d_ws;
    size_t p = 0;
    auto alloc = [&](size_t elems) { size_t o = p; p += (elems + 63) & ~63ull; return o; };
    float* dinv   = ws + alloc(n);
    int*   rowptr = (int*)(ws + alloc((size_t)n + 1));
    int*   btot   = (int*)(ws + alloc(NBKT));
    int*   bbase  = (int*)(ws + alloc(NBKT));
    int2*  csr    = (int2*)(ws + alloc((size_t)E * 2));
    float* t1     = ws + alloc((size_t)n * 64);            // Â z (f32), matmul1 input
    uint2* zs     = (uint2*)(ws + alloc((size_t)n * 32));  // bf16 pre-scaled operand
    // region X: tmp+hist (preprocessing) then h (layers) — tmp dead before h written
    float* X      = ws + alloc((size_t)n * 128);
    int2*  tmp    = (int2*)X;                       // E int2
    int*   hist   = (int*)(X + (size_t)E * 2);      // NBKT*G1 ints
    float* h      = X;
    (void)ws_size;

    // ---- preprocessing: counting sort by dst, zero global atomics ----
    hist_kernel<<<G1, 256, 0, stream>>>(dst, hist, E, G1, NBKT);
    bscan_kernel<<<NBKT, 64, 0, stream>>>(hist, btot, G1);
    tscan_kernel<<<1, 512, 0, stream>>>(btot, bbase, NBKT);
    scatter_kernel<<<G1, 256, 0, stream>>>(src, dst, ea, hist, bbase, tmp, E, G1, NBKT);
    finalize_kernel<<<NBKT, 256, 0, stream>>>(tmp, bbase, btot, rowptr, dinv, csr, n, E);
    convs_kernel<<<(n * 16 + 255) / 256, 256, 0, stream>>>(z, dinv, zs, n);

    const int gblocks = (n + 3) / 4;
    // ---- layer 1: t1 = Â z ; h = relu(t1 @ W1 + b1) ----
    gaggb_kernel<false><<<gblocks, 256, 0, stream>>>(rowptr, (const long long*)csr,
                                                     dinv, zs, nullptr, t1, n);
    matmulE_kernel<64, 128, true, true, false><<<(n + 7) / 8, 256, 0, stream>>>(
        t1, W1, b1, nullptr, h, n);

    // ---- layer 2: hs = bf16(dinv*(h @ W2)) (reuses zs) ; out = gather + b2 ----
    matmulE_kernel<128, 64, false, false, true><<<(n + 15) / 16, 256, 0, stream>>>(
        h, W2, nullptr, dinv, zs, n);
    gaggb_kernel<true><<<gblocks, 256, 0, stream>>>(rowptr, (const long long*)csr,
                                                    dinv, zs, b2, out, n);
}

// Round 11
// 180.106 us; speedup vs baseline: 1.5381x; 1.0766x over previous
//
#include <hip/hip_runtime.h>

// 2-layer GCN, CSR-gather formulation, v11.
//   Â = D^{-1/2}(A+I)D^{-1/2},  out = Â(relu(Â z W1 + b1))W2 + b2
// layer1: t1 = Â z (64-wide); layer2: hs = bf16(dinv*(relu(t1@W1+b1)@W2)), out = gather+b2.
// v6: CSR build via two-level LDS counting sort by dst — zero global atomics.
// v7: bf16 gather operand, full 128B row per request (request-service bound).
// v9-kept: operand pre-scaled by dinv (wscale deleted).
// v11: nt-CSR REVERTED (nt skipped L2 alloc -> 8x CSR line re-fetch, +11us);
// matmul1+matmul2 fused (h only in LDS, saves 51MB traffic); convs fused into
// finalize (block already owns its nodes' dinv).

#define NPB 128   // nodes per fine bucket (dst & 127 is the in-bucket id)
#define CH  4096  // edges per chunk block in hist/scatter passes

__device__ __forceinline__ float4 ld4(const float* p) {
    return *reinterpret_cast<const float4*>(p);
}

// round-to-nearest-even f32 -> bf16 (as ushort in low bits)
__device__ __forceinline__ unsigned bfr(float f) {
    unsigned u = __float_as_uint(f);
    return (u + 0x7FFFu + ((u >> 16) & 1u)) >> 16;
}
// unpack 4 bf16 (uint2) -> 4 f32
__device__ __forceinline__ void bf4(uint2 v, float& f0, float& f1, float& f2, float& f3) {
    f0 = __uint_as_float(v.x << 16);
    f1 = __uint_as_float(v.x & 0xFFFF0000u);
    f2 = __uint_as_float(v.y << 16);
    f3 = __uint_as_float(v.y & 0xFFFF0000u);
}

// ---- K1: coarse histogram per chunk (LDS), bucket-major out: hist[b*G1+g] ----
__global__ __launch_bounds__(256) void hist_kernel(const int* __restrict__ dst,
                                                   int* __restrict__ hist,
                                                   int E, int G1, int NBKT) {
    __shared__ int lh[512];
    for (int i = threadIdx.x; i < NBKT; i += 256) lh[i] = 0;
    __syncthreads();
    int g = blockIdx.x;
    int beg = g * CH, end = min(beg + CH, E);
    for (int j = beg + (int)threadIdx.x; j < end; j += 256)
        atomicAdd(&lh[dst[j] / NPB], 1);
    __syncthreads();
    for (int i = threadIdx.x; i < NBKT; i += 256) hist[(size_t)i * G1 + g] = lh[i];
}

// ---- K2a: per-bucket exclusive scan across chunks (in place); btot[b] = total ----
__global__ __launch_bounds__(64) void bscan_kernel(int* __restrict__ hist,
                                                   int* __restrict__ btot, int G1) {
    int b = blockIdx.x;
    int* row = hist + (size_t)b * G1;
    int lane = threadIdx.x;
    int carry = 0;
    for (int g0 = 0; g0 < G1; g0 += 64) {
        int g = g0 + lane;
        int v = (g < G1) ? row[g] : 0;
        int incl = v;
#pragma unroll
        for (int off = 1; off < 64; off <<= 1) {
            int u = __shfl_up(incl, off, 64);
            if (lane >= off) incl += u;
        }
        if (g < G1) row[g] = carry + incl - v;
        carry += __shfl(incl, 63, 64);
    }
    if (lane == 0) btot[b] = carry;
}

// ---- K2b: exclusive scan of bucket totals -> bucket bases (NBKT <= 512) ----
__global__ __launch_bounds__(512) void tscan_kernel(const int* __restrict__ btot,
                                                    int* __restrict__ bbase, int NBKT) {
    __shared__ int ws[8];
    int t = threadIdx.x;
    int v = (t < NBKT) ? btot[t] : 0;
    int lane = t & 63, wid = t >> 6;
    int incl = v;
#pragma unroll
    for (int off = 1; off < 64; off <<= 1) {
        int u = __shfl_up(incl, off, 64);
        if (lane >= off) incl += u;
    }
    if (lane == 63) ws[wid] = incl;
    __syncthreads();
    int woff = 0;
#pragma unroll
    for (int w = 0; w < 8; ++w) if (w < wid) woff += ws[w];
    if (t < NBKT) bbase[t] = woff + incl - v;
}

// ---- K3: scatter edges into bucket-grouped tmp via LDS cursors ----
__global__ __launch_bounds__(256) void scatter_kernel(const int* __restrict__ src,
                                                      const int* __restrict__ dst,
                                                      const float* __restrict__ ew,
                                                      const int* __restrict__ hist,
                                                      const int* __restrict__ bbase,
                                                      int2* __restrict__ tmp,
                                                      int E, int G1, int NBKT) {
    __shared__ int cursor[512];
    int g = blockIdx.x;
    for (int i = threadIdx.x; i < NBKT; i += 256)
        cursor[i] = bbase[i] + hist[(size_t)i * G1 + g];
    __syncthreads();
    int beg = g * CH, end = min(beg + CH, E);
    for (int j = beg + (int)threadIdx.x; j < end; j += 256) {
        int d = dst[j];
        int b = d / NPB;
        int pos = atomicAdd(&cursor[b], 1);
        tmp[pos] = make_int2(((d & (NPB - 1)) << 24) | src[j], __float_as_int(ew[j]));
    }
}

// ---- K4: per-bucket finalize: rowptr, dinv, final CSR {src, ew}, zs rows ----
__global__ __launch_bounds__(256) void finalize_kernel(const int2* __restrict__ tmp,
                                                       const int* __restrict__ bbase,
                                                       const int* __restrict__ btot,
                                                       const float* __restrict__ z,
                                                       int* __restrict__ rowptr,
                                                       float* __restrict__ dinv,
                                                       int2* __restrict__ csr,
                                                       uint2* __restrict__ zs,
                                                       int n, int E) {
    __shared__ unsigned int hist[NPB];
    __shared__ float dvl[NPB];
    __shared__ int wsum_[2];
    int b = blockIdx.x;
    int base = bbase[b];
    int cnt  = btot[b];
    int tid  = threadIdx.x;
    if (tid < NPB) hist[tid] = 0;
    __syncthreads();
    // phase A: packed count + weighted degree
    for (int j = tid; j < cnt; j += 256) {
        int2 t = tmp[base + j];
        unsigned dlow = ((unsigned)t.x) >> 24;
        unsigned wfix = (unsigned)(__int_as_float(t.y) * 16384.0f);
        atomicAdd(&hist[dlow], (1u << 24) | wfix);
    }
    __syncthreads();
    int c = 0, incl = 0;
    unsigned pk = 0;
    if (tid < NPB) {
        pk = hist[tid];
        c = (int)(pk >> 24);
        incl = c;
#pragma unroll
        for (int off = 1; off < 64; off <<= 1) {
            int u = __shfl_up(incl, off, 64);
            if ((tid & 63) >= off) incl += u;
        }
        if ((tid & 63) == 63) wsum_[tid >> 6] = incl;
    }
    __syncthreads();
    if (tid < NPB) {
        int woff = (tid >= 64) ? wsum_[0] : 0;
        int excl = woff + incl - c;
        int node = b * NPB + tid;
        float dv = 0.f;
        if (node < n) {
            rowptr[node] = base + excl;
            float wdeg = (float)(pk & 0xFFFFFFu) * (1.0f / 16384.0f);
            dv = rsqrtf(wdeg + 1.0f);
            dinv[node] = dv;
        }
        dvl[tid]  = dv;
        hist[tid] = (unsigned)excl;   // becomes cursor for phase B
    }
    if (b == 0 && tid == 0) rowptr[n] = E;
    __syncthreads();
    // phase B: place edges within bucket
    for (int j = tid; j < cnt; j += 256) {
        int2 t = tmp[base + j];
        unsigned dlow = ((unsigned)t.x) >> 24;
        int srcv = t.x & 0xFFFFFF;
        int lr = (int)atomicAdd(&hist[dlow], 1u);
        csr[base + lr] = make_int2(srcv, t.y);
    }
    // phase C (fused convs): zs[node] = bf16(dinv*z[node]) for this block's nodes
    for (int t = tid; t < NPB * 16; t += 256) {
        int li = t >> 4;
        int node = b * NPB + li;
        if (node < n) {
            int k = t & 15;
            float dv = dvl[li];
            float4 f = ld4(z + (size_t)node * 64 + k * 4);
            zs[(size_t)node * 16 + k] =
                make_uint2(bfr(dv * f.x) | (bfr(dv * f.y) << 16),
                           bfr(dv * f.z) | (bfr(dv * f.w) << 16));
        }
    }
}

// ---- gather-aggregate (F=64, bf16 pre-scaled operand): one wave per dst row ----
// Lane l: eg = l>>4 (edge subgroup), fq = l&15 (feature uint2 = 4 bf16).
// out[row] = (BIAS? b : 0) + dv * ( sum_j ew_j * Hp[src_j] + Hp[row] )
template<bool BIAS>
__global__ __launch_bounds__(256) void gaggb_kernel(const int* __restrict__ rowptr,
                                                    const int2* __restrict__ csr,
                                                    const float* __restrict__ dinv,
                                                    const uint2* __restrict__ Hp,
                                                    const float* __restrict__ b,
                                                    float* __restrict__ out, int n) {
    int row  = (blockIdx.x * 256 + threadIdx.x) >> 6;
    int lane = threadIdx.x & 63;
    if (row >= n) return;
    int eg = lane >> 4, fq = lane & 15;
    int beg = rowptr[row], end = rowptr[row + 1];
    float dv = dinv[row];

    float ax = 0.f, ay = 0.f, az = 0.f, aw = 0.f;
    float f0, f1, f2, f3;
    int j = beg;
    for (; j + 16 <= end; j += 16) {
        int2 m0 = csr[j + eg];
        int2 m1 = csr[j + eg + 4];
        int2 m2 = csr[j + eg + 8];
        int2 m3 = csr[j + eg + 12];
        uint2 v0 = Hp[(size_t)(unsigned)(m0.x) * 16 + fq];
        uint2 v1 = Hp[(size_t)(unsigned)(m1.x) * 16 + fq];
        uint2 v2 = Hp[(size_t)(unsigned)(m2.x) * 16 + fq];
        uint2 v3 = Hp[(size_t)(unsigned)(m3.x) * 16 + fq];
        float w0 = __int_as_float(m0.y), w1 = __int_as_float(m1.y);
        float w2 = __int_as_float(m2.y), w3 = __int_as_float(m3.y);
        bf4(v0, f0, f1, f2, f3);
        ax += w0 * f0; ay += w0 * f1; az += w0 * f2; aw += w0 * f3;
        bf4(v1, f0, f1, f2, f3);
        ax += w1 * f0; ay += w1 * f1; az += w1 * f2; aw += w1 * f3;
        bf4(v2, f0, f1, f2, f3);
        ax += w2 * f0; ay += w2 * f1; az += w2 * f2; aw += w2 * f3;
        bf4(v3, f0, f1, f2, f3);
        ax += w3 * f0; ay += w3 * f1; az += w3 * f2; aw += w3 * f3;
    }
    for (; j + 4 <= end; j += 4) {
        int2 m0 = csr[j + eg];
        float w0 = __int_as_float(m0.y);
        uint2 v0 = Hp[(size_t)(unsigned)(m0.x) * 16 + fq];
        bf4(v0, f0, f1, f2, f3);
        ax += w0 * f0; ay += w0 * f1; az += w0 * f2; aw += w0 * f3;
    }
    if (j < end) {
        int idx = j + eg;
        if (idx < end) {
            int2 m0 = csr[idx];
            float w0 = __int_as_float(m0.y);
            uint2 v0 = Hp[(size_t)(unsigned)(m0.x) * 16 + fq];
            bf4(v0, f0, f1, f2, f3);
            ax += w0 * f0; ay += w0 * f1; az += w0 * f2; aw += w0 * f3;
        }
    }
    // combine the 4 edge subgroups (lane bits 4,5)
    ax += __shfl_xor(ax, 16, 64); ay += __shfl_xor(ay, 16, 64);
    az += __shfl_xor(az, 16, 64); aw += __shfl_xor(aw, 16, 64);
    ax += __shfl_xor(ax, 32, 64); ay += __shfl_xor(ay, 32, 64);
    az += __shfl_xor(az, 32, 64); aw += __shfl_xor(aw, 32, 64);

    if (eg == 0) {
        uint2 sv = Hp[(size_t)row * 16 + fq];   // self term (already dinv-scaled)
        float s0, s1, s2, s3;
        bf4(sv, s0, s1, s2, s3);
        float4 o;
        o.x = dv * (ax + s0);
        o.y = dv * (ay + s1);
        o.z = dv * (az + s2);
        o.w = dv * (aw + s3);
        if (BIAS) {
            float4 bb = ld4(b + fq * 4);
            o.x += bb.x; o.y += bb.y; o.z += bb.z; o.w += bb.w;
        }
        reinterpret_cast<float4*>(out)[(size_t)row * 16 + fq] = o;
    }
}

// ---- fused dense: hs[r] = bf16(dinv[r]*(relu(t1[r]@W1 + b1)@W2)), h in LDS ----
// 256 thr; 8 rows per iteration; grid-strided so W1/W2 staged once per block.
__global__ __launch_bounds__(256) void fusedmm_kernel(const float* __restrict__ t1,
                                                      const float* __restrict__ W1,
                                                      const float* __restrict__ b1,
                                                      const float* __restrict__ W2,
                                                      const float* __restrict__ dinv,
                                                      unsigned* __restrict__ hs,
                                                      int n) {
    __shared__ float W1s[64 * 128];   // 32 KB
    __shared__ float W2s[128 * 64];   // 32 KB
    __shared__ float b1s[128];
    __shared__ float hbuf[8][128];    // 4 KB
    for (int i = threadIdx.x; i < 64 * 128 / 4; i += 256)
        reinterpret_cast<float4*>(W1s)[i] = reinterpret_cast<const float4*>(W1)[i];
    for (int i = threadIdx.x; i < 128 * 64 / 4; i += 256)
        reinterpret_cast<float4*>(W2s)[i] = reinterpret_cast<const float4*>(W2)[i];
    if (threadIdx.x < 128) b1s[threadIdx.x] = b1[threadIdx.x];
    __syncthreads();

    int tr = threadIdx.x >> 5;   // row-in-group 0..7
    int q  = threadIdx.x & 31;   // 0..31
    int nrb = (n + 7) >> 3;
    for (int rb = blockIdx.x; rb < nrb; rb += gridDim.x) {
        int r = rb * 8 + tr;
        // phase 1: hbuf[tr] = relu(t1[r] @ W1 + b1)   (4 outputs/thread)
        if (r < n) {
            const float* xr = t1 + (size_t)r * 64;
            float ax = 0.f, ay = 0.f, az = 0.f, aw = 0.f;
#pragma unroll
            for (int k = 0; k < 64; k += 4) {
                float4 a = ld4(xr + k);
                float4 w0 = ld4(&W1s[(k + 0) * 128 + q * 4]);
                float4 w1 = ld4(&W1s[(k + 1) * 128 + q * 4]);
                float4 w2 = ld4(&W1s[(k + 2) * 128 + q * 4]);
                float4 w3 = ld4(&W1s[(k + 3) * 128 + q * 4]);
                ax += a.x * w0.x + a.y * w1.x + a.z * w2.x + a.w * w3.x;
                ay += a.x * w0.y + a.y * w1.y + a.z * w2.y + a.w * w3.y;
                az += a.x * w0.z + a.y * w1.z + a.z * w2.z + a.w * w3.z;
                aw += a.x * w0.w + a.y * w1.w + a.z * w2.w + a.w * w3.w;
            }
            float4 bb = ld4(b1s + q * 4);
            hbuf[tr][q * 4 + 0] = fmaxf(ax + bb.x, 0.f);
            hbuf[tr][q * 4 + 1] = fmaxf(ay + bb.y, 0.f);
            hbuf[tr][q * 4 + 2] = fmaxf(az + bb.z, 0.f);
            hbuf[tr][q * 4 + 3] = fmaxf(aw + bb.w, 0.f);
        }
        __syncthreads();
        // phase 2: hs[r] cols 2q,2q+1 = bf16(dinv[r] * (hbuf[tr] @ W2))
        if (r < n) {
            float a0 = 0.f, a1 = 0.f;
            const float* hr = hbuf[tr];
#pragma unroll
            for (int k = 0; k < 128; ++k) {
                float hv = hr[k];
                float2 w = *reinterpret_cast<const float2*>(&W2s[k * 64 + q * 2]);
                a0 += hv * w.x;
                a1 += hv * w.y;
            }
            float dvr = dinv[r];
            hs[(size_t)r * 32 + q] = bfr(dvr * a0) | (bfr(dvr * a1) << 16);
        }
        __syncthreads();
    }
}

extern "C" void kernel_launch(void* const* d_in, const int* in_sizes, int n_in,
                              void* d_out, int out_size, void* d_ws, size_t ws_size,
                              hipStream_t stream) {
    const float* z  = (const float*)d_in[0];
    const int*   ei = (const int*)d_in[1];
    const float* ea = (const float*)d_in[2];
    const float* W1 = (const float*)d_in[3];
    const float* b1 = (const float*)d_in[4];
    const float* W2 = (const float*)d_in[5];
    const float* b2 = (const float*)d_in[6];
    float* out = (float*)d_out;

    const int n = in_sizes[0] / 64;   // LAT = 64
    const int E = in_sizes[2];
    const int* src = ei;
    const int* dst = ei + E;
    const int NBKT = (n + NPB - 1) / NPB;   // 391 for n=50000 (<=512 required)
    const int G1   = (E + CH - 1) / CH;     // chunk blocks

    float* ws = (float*)d_ws;
    size_t p = 0;
    auto alloc = [&](size_t elems) { size_t o = p; p += (elems + 63) & ~63ull; return o; };
    float* dinv   = ws + alloc(n);
    int*   rowptr = (int*)(ws + alloc((size_t)n + 1));
    int*   btot   = (int*)(ws + alloc(NBKT));
    int*   bbase  = (int*)(ws + alloc(NBKT));
    int2*  csr    = (int2*)(ws + alloc((size_t)E * 2));
    float* t1     = ws + alloc((size_t)n * 64);            // Â z (f32)
    uint2* zs     = (uint2*)(ws + alloc((size_t)n * 32));  // bf16 pre-scaled operand
    // region X: tmp + hist (preprocessing only)
    float* X      = ws + alloc((size_t)E * 2 + (size_t)NBKT * G1 + 64);
    int2*  tmp    = (int2*)X;                       // E int2
    int*   hist   = (int*)(X + (size_t)E * 2);      // NBKT*G1 ints
    (void)ws_size;

    // ---- preprocessing: counting sort by dst, zero global atomics ----
    hist_kernel<<<G1, 256, 0, stream>>>(dst, hist, E, G1, NBKT);
    bscan_kernel<<<NBKT, 64, 0, stream>>>(hist, btot, G1);
    tscan_kernel<<<1, 512, 0, stream>>>(btot, bbase, NBKT);
    scatter_kernel<<<G1, 256, 0, stream>>>(src, dst, ea, hist, bbase, tmp, E, G1, NBKT);
    finalize_kernel<<<NBKT, 256, 0, stream>>>(tmp, bbase, btot, z, rowptr, dinv,
                                              csr, zs, n, E);

    const int gblocks = (n + 3) / 4;
    // ---- layer 1 gather: t1 = Â z ----
    gaggb_kernel<false><<<gblocks, 256, 0, stream>>>(rowptr, csr, dinv, zs,
                                                     nullptr, t1, n);
    // ---- fused dense: hs = bf16(dinv*(relu(t1@W1+b1)@W2)) (reuses zs) ----
    fusedmm_kernel<<<1024, 256, 0, stream>>>(t1, W1, b1, W2, dinv,
                                             (unsigned*)zs, n);
    // ---- layer 2 gather: out = Â hs + b2 ----
    gaggb_kernel<true><<<gblocks, 256, 0, stream>>>(rowptr, csr, dinv, zs,
                                                    b2, out, n);
}

// Round 12
// 177.859 us; speedup vs baseline: 1.5575x; 1.0126x over previous
//
#include <hip/hip_runtime.h>

// 2-layer GCN, CSR-gather formulation, v12.
//   Â = D^{-1/2}(A+I)D^{-1/2},  out = Â(relu(Â z W1 + b1))W2 + b2
// layer1: t1 = Â z ; h = relu(t1@W1+b1); layer2: hs = bf16(dinv*(h@W2)), out = gather+b2.
// v6: CSR build via two-level LDS counting sort by dst — zero global atomics.
// v7: bf16 gather operand, full 128B row per request (request-service bound).
// v9: operand pre-scaled by dinv. v11: convs fused into finalize; plain CSR loads
// (nt skipped L2 alloc -> 8x line re-fetch). v12: dense UNFUSED back to two
// single-row matmuls (v11's fused 68KB-LDS kernel ran at 19% occupancy, 63us vs
// ~28us separate; the 51MB h-traffic saving couldn't pay for the occupancy loss).

#define NPB 128   // nodes per fine bucket (dst & 127 is the in-bucket id)
#define CH  4096  // edges per chunk block in hist/scatter passes

__device__ __forceinline__ float4 ld4(const float* p) {
    return *reinterpret_cast<const float4*>(p);
}

// round-to-nearest-even f32 -> bf16 (as ushort in low bits)
__device__ __forceinline__ unsigned bfr(float f) {
    unsigned u = __float_as_uint(f);
    return (u + 0x7FFFu + ((u >> 16) & 1u)) >> 16;
}
// unpack 4 bf16 (uint2) -> 4 f32
__device__ __forceinline__ void bf4(uint2 v, float& f0, float& f1, float& f2, float& f3) {
    f0 = __uint_as_float(v.x << 16);
    f1 = __uint_as_float(v.x & 0xFFFF0000u);
    f2 = __uint_as_float(v.y << 16);
    f3 = __uint_as_float(v.y & 0xFFFF0000u);
}

// ---- K1: coarse histogram per chunk (LDS), bucket-major out: hist[b*G1+g] ----
__global__ __launch_bounds__(256) void hist_kernel(const int* __restrict__ dst,
                                                   int* __restrict__ hist,
                                                   int E, int G1, int NBKT) {
    __shared__ int lh[512];
    for (int i = threadIdx.x; i < NBKT; i += 256) lh[i] = 0;
    __syncthreads();
    int g = blockIdx.x;
    int beg = g * CH, end = min(beg + CH, E);
    for (int j = beg + (int)threadIdx.x; j < end; j += 256)
        atomicAdd(&lh[dst[j] / NPB], 1);
    __syncthreads();
    for (int i = threadIdx.x; i < NBKT; i += 256) hist[(size_t)i * G1 + g] = lh[i];
}

// ---- K2a: per-bucket exclusive scan across chunks (in place); btot[b] = total ----
__global__ __launch_bounds__(64) void bscan_kernel(int* __restrict__ hist,
                                                   int* __restrict__ btot, int G1) {
    int b = blockIdx.x;
    int* row = hist + (size_t)b * G1;
    int lane = threadIdx.x;
    int carry = 0;
    for (int g0 = 0; g0 < G1; g0 += 64) {
        int g = g0 + lane;
        int v = (g < G1) ? row[g] : 0;
        int incl = v;
#pragma unroll
        for (int off = 1; off < 64; off <<= 1) {
            int u = __shfl_up(incl, off, 64);
            if (lane >= off) incl += u;
        }
        if (g < G1) row[g] = carry + incl - v;
        carry += __shfl(incl, 63, 64);
    }
    if (lane == 0) btot[b] = carry;
}

// ---- K2b: exclusive scan of bucket totals -> bucket bases (NBKT <= 512) ----
__global__ __launch_bounds__(512) void tscan_kernel(const int* __restrict__ btot,
                                                    int* __restrict__ bbase, int NBKT) {
    __shared__ int ws[8];
    int t = threadIdx.x;
    int v = (t < NBKT) ? btot[t] : 0;
    int lane = t & 63, wid = t >> 6;
    int incl = v;
#pragma unroll
    for (int off = 1; off < 64; off <<= 1) {
        int u = __shfl_up(incl, off, 64);
        if (lane >= off) incl += u;
    }
    if (lane == 63) ws[wid] = incl;
    __syncthreads();
    int woff = 0;
#pragma unroll
    for (int w = 0; w < 8; ++w) if (w < wid) woff += ws[w];
    if (t < NBKT) bbase[t] = woff + incl - v;
}

// ---- K3: scatter edges into bucket-grouped tmp via LDS cursors ----
__global__ __launch_bounds__(256) void scatter_kernel(const int* __restrict__ src,
                                                      const int* __restrict__ dst,
                                                      const float* __restrict__ ew,
                                                      const int* __restrict__ hist,
                                                      const int* __restrict__ bbase,
                                                      int2* __restrict__ tmp,
                                                      int E, int G1, int NBKT) {
    __shared__ int cursor[512];
    int g = blockIdx.x;
    for (int i = threadIdx.x; i < NBKT; i += 256)
        cursor[i] = bbase[i] + hist[(size_t)i * G1 + g];
    __syncthreads();
    int beg = g * CH, end = min(beg + CH, E);
    for (int j = beg + (int)threadIdx.x; j < end; j += 256) {
        int d = dst[j];
        int b = d / NPB;
        int pos = atomicAdd(&cursor[b], 1);
        tmp[pos] = make_int2(((d & (NPB - 1)) << 24) | src[j], __float_as_int(ew[j]));
    }
}

// ---- K4: per-bucket finalize: rowptr, dinv, final CSR {src, ew}, zs rows ----
__global__ __launch_bounds__(256) void finalize_kernel(const int2* __restrict__ tmp,
                                                       const int* __restrict__ bbase,
                                                       const int* __restrict__ btot,
                                                       const float* __restrict__ z,
                                                       int* __restrict__ rowptr,
                                                       float* __restrict__ dinv,
                                                       int2* __restrict__ csr,
                                                       uint2* __restrict__ zs,
                                                       int n, int E) {
    __shared__ unsigned int hist[NPB];
    __shared__ float dvl[NPB];
    __shared__ int wsum_[2];
    int b = blockIdx.x;
    int base = bbase[b];
    int cnt  = btot[b];
    int tid  = threadIdx.x;
    if (tid < NPB) hist[tid] = 0;
    __syncthreads();
    // phase A: packed count + weighted degree
    for (int j = tid; j < cnt; j += 256) {
        int2 t = tmp[base + j];
        unsigned dlow = ((unsigned)t.x) >> 24;
        unsigned wfix = (unsigned)(__int_as_float(t.y) * 16384.0f);
        atomicAdd(&hist[dlow], (1u << 24) | wfix);
    }
    __syncthreads();
    int c = 0, incl = 0;
    unsigned pk = 0;
    if (tid < NPB) {
        pk = hist[tid];
        c = (int)(pk >> 24);
        incl = c;
#pragma unroll
        for (int off = 1; off < 64; off <<= 1) {
            int u = __shfl_up(incl, off, 64);
            if ((tid & 63) >= off) incl += u;
        }
        if ((tid & 63) == 63) wsum_[tid >> 6] = incl;
    }
    __syncthreads();
    if (tid < NPB) {
        int woff = (tid >= 64) ? wsum_[0] : 0;
        int excl = woff + incl - c;
        int node = b * NPB + tid;
        float dv = 0.f;
        if (node < n) {
            rowptr[node] = base + excl;
            float wdeg = (float)(pk & 0xFFFFFFu) * (1.0f / 16384.0f);
            dv = rsqrtf(wdeg + 1.0f);
            dinv[node] = dv;
        }
        dvl[tid]  = dv;
        hist[tid] = (unsigned)excl;   // becomes cursor for phase B
    }
    if (b == 0 && tid == 0) rowptr[n] = E;
    __syncthreads();
    // phase B: place edges within bucket
    for (int j = tid; j < cnt; j += 256) {
        int2 t = tmp[base + j];
        unsigned dlow = ((unsigned)t.x) >> 24;
        int srcv = t.x & 0xFFFFFF;
        int lr = (int)atomicAdd(&hist[dlow], 1u);
        csr[base + lr] = make_int2(srcv, t.y);
    }
    // phase C (fused convs): zs[node] = bf16(dinv*z[node]) for this block's nodes
    for (int t = tid; t < NPB * 16; t += 256) {
        int li = t >> 4;
        int node = b * NPB + li;
        if (node < n) {
            int k = t & 15;
            float dv = dvl[li];
            float4 f = ld4(z + (size_t)node * 64 + k * 4);
            zs[(size_t)node * 16 + k] =
                make_uint2(bfr(dv * f.x) | (bfr(dv * f.y) << 16),
                           bfr(dv * f.z) | (bfr(dv * f.w) << 16));
        }
    }
}

// ---- gather-aggregate (F=64, bf16 pre-scaled operand): one wave per dst row ----
// Lane l: eg = l>>4 (edge subgroup), fq = l&15 (feature uint2 = 4 bf16).
// out[row] = (BIAS? b : 0) + dv * ( sum_j ew_j * Hp[src_j] + Hp[row] )
template<bool BIAS>
__global__ __launch_bounds__(256) void gaggb_kernel(const int* __restrict__ rowptr,
                                                    const int2* __restrict__ csr,
                                                    const float* __restrict__ dinv,
                                                    const uint2* __restrict__ Hp,
                                                    const float* __restrict__ b,
                                                    float* __restrict__ out, int n) {
    int row  = (blockIdx.x * 256 + threadIdx.x) >> 6;
    int lane = threadIdx.x & 63;
    if (row >= n) return;
    int eg = lane >> 4, fq = lane & 15;
    int beg = rowptr[row], end = rowptr[row + 1];
    float dv = dinv[row];

    float ax = 0.f, ay = 0.f, az = 0.f, aw = 0.f;
    float f0, f1, f2, f3;
    int j = beg;
    for (; j + 16 <= end; j += 16) {
        int2 m0 = csr[j + eg];
        int2 m1 = csr[j + eg + 4];
        int2 m2 = csr[j + eg + 8];
        int2 m3 = csr[j + eg + 12];
        uint2 v0 = Hp[(size_t)(unsigned)(m0.x) * 16 + fq];
        uint2 v1 = Hp[(size_t)(unsigned)(m1.x) * 16 + fq];
        uint2 v2 = Hp[(size_t)(unsigned)(m2.x) * 16 + fq];
        uint2 v3 = Hp[(size_t)(unsigned)(m3.x) * 16 + fq];
        float w0 = __int_as_float(m0.y), w1 = __int_as_float(m1.y);
        float w2 = __int_as_float(m2.y), w3 = __int_as_float(m3.y);
        bf4(v0, f0, f1, f2, f3);
        ax += w0 * f0; ay += w0 * f1; az += w0 * f2; aw += w0 * f3;
        bf4(v1, f0, f1, f2, f3);
        ax += w1 * f0; ay += w1 * f1; az += w1 * f2; aw += w1 * f3;
        bf4(v2, f0, f1, f2, f3);
        ax += w2 * f0; ay += w2 * f1; az += w2 * f2; aw += w2 * f3;
        bf4(v3, f0, f1, f2, f3);
        ax += w3 * f0; ay += w3 * f1; az += w3 * f2; aw += w3 * f3;
    }
    for (; j + 4 <= end; j += 4) {
        int2 m0 = csr[j + eg];
        float w0 = __int_as_float(m0.y);
        uint2 v0 = Hp[(size_t)(unsigned)(m0.x) * 16 + fq];
        bf4(v0, f0, f1, f2, f3);
        ax += w0 * f0; ay += w0 * f1; az += w0 * f2; aw += w0 * f3;
    }
    if (j < end) {
        int idx = j + eg;
        if (idx < end) {
            int2 m0 = csr[idx];
            float w0 = __int_as_float(m0.y);
            uint2 v0 = Hp[(size_t)(unsigned)(m0.x) * 16 + fq];
            bf4(v0, f0, f1, f2, f3);
            ax += w0 * f0; ay += w0 * f1; az += w0 * f2; aw += w0 * f3;
        }
    }
    // combine the 4 edge subgroups (lane bits 4,5)
    ax += __shfl_xor(ax, 16, 64); ay += __shfl_xor(ay, 16, 64);
    az += __shfl_xor(az, 16, 64); aw += __shfl_xor(aw, 16, 64);
    ax += __shfl_xor(ax, 32, 64); ay += __shfl_xor(ay, 32, 64);
    az += __shfl_xor(az, 32, 64); aw += __shfl_xor(aw, 32, 64);

    if (eg == 0) {
        uint2 sv = Hp[(size_t)row * 16 + fq];   // self term (already dinv-scaled)
        float s0, s1, s2, s3;
        bf4(sv, s0, s1, s2, s3);
        float4 o;
        o.x = dv * (ax + s0);
        o.y = dv * (ay + s1);
        o.z = dv * (az + s2);
        o.w = dv * (aw + s3);
        if (BIAS) {
            float4 bb = ld4(b + fq * 4);
            o.x += bb.x; o.y += bb.y; o.z += bb.z; o.w += bb.w;
        }
        reinterpret_cast<float4*>(out)[(size_t)row * 16 + fq] = o;
    }
}

// ---- dense matmul (single row/thread): Y = (X @ W) [+b] [relu] ----
// OUTB: Y = bf16(dinv[r] * row) packed uint2, contiguous [n][FOUT/4].
template<int FIN, int FOUT, bool RELU, bool BIAS, bool OUTB>
__global__ __launch_bounds__(256) void matmulE_kernel(const float* __restrict__ X,
                                                      const float* __restrict__ W,
                                                      const float* __restrict__ b,
                                                      const float* __restrict__ dinv,
                                                      void* __restrict__ Y, int n) {
    constexpr int QPR = FOUT / 4;     // threads per row (4 outputs each)
    constexpr int RPB = 256 / QPR;    // rows per block
    __shared__ float Ws[FIN * FOUT];
    for (int i = threadIdx.x; i < FIN * FOUT / 4; i += 256)
        reinterpret_cast<float4*>(Ws)[i] = reinterpret_cast<const float4*>(W)[i];
    __syncthreads();

    int r = blockIdx.x * RPB + threadIdx.x / QPR;
    int q = threadIdx.x % QPR;
    if (r >= n) return;
    const float* xr = X + (size_t)r * FIN;

    float ax = 0.f, ay = 0.f, az = 0.f, aw = 0.f;
#pragma unroll
    for (int k = 0; k < FIN; k += 4) {
        float4 a = ld4(xr + k);
        float4 w0 = ld4(&Ws[(k + 0) * FOUT + q * 4]);
        float4 w1 = ld4(&Ws[(k + 1) * FOUT + q * 4]);
        float4 w2 = ld4(&Ws[(k + 2) * FOUT + q * 4]);
        float4 w3 = ld4(&Ws[(k + 3) * FOUT + q * 4]);
        ax += a.x * w0.x + a.y * w1.x + a.z * w2.x + a.w * w3.x;
        ay += a.x * w0.y + a.y * w1.y + a.z * w2.y + a.w * w3.y;
        az += a.x * w0.z + a.y * w1.z + a.z * w2.z + a.w * w3.z;
        aw += a.x * w0.w + a.y * w1.w + a.z * w2.w + a.w * w3.w;
    }
    float4 o = make_float4(ax, ay, az, aw);
    if (BIAS) {
        float4 bb = ld4(b + q * 4);
        o.x += bb.x; o.y += bb.y; o.z += bb.z; o.w += bb.w;
    }
    if (RELU) {
        o.x = fmaxf(o.x, 0.f); o.y = fmaxf(o.y, 0.f);
        o.z = fmaxf(o.z, 0.f); o.w = fmaxf(o.w, 0.f);
    }
    if (OUTB) {
        float dvr = dinv[r];
        o.x *= dvr; o.y *= dvr; o.z *= dvr; o.w *= dvr;
        uint2 pv = make_uint2(bfr(o.x) | (bfr(o.y) << 16),
                              bfr(o.z) | (bfr(o.w) << 16));
        reinterpret_cast<uint2*>(Y)[(size_t)r * QPR + q] = pv;
    } else {
        reinterpret_cast<float4*>(Y)[(size_t)r * QPR + q] = o;
    }
}

extern "C" void kernel_launch(void* const* d_in, const int* in_sizes, int n_in,
                              void* d_out, int out_size, void* d_ws, size_t ws_size,
                              hipStream_t stream) {
    const float* z  = (const float*)d_in[0];
    const int*   ei = (const int*)d_in[1];
    const float* ea = (const float*)d_in[2];
    const float* W1 = (const float*)d_in[3];
    const float* b1 = (const float*)d_in[4];
    const float* W2 = (const float*)d_in[5];
    const float* b2 = (const float*)d_in[6];
    float* out = (float*)d_out;

    const int n = in_sizes[0] / 64;   // LAT = 64
    const int E = in_sizes[2];
    const int* src = ei;
    const int* dst = ei + E;
    const int NBKT = (n + NPB - 1) / NPB;   // 391 for n=50000 (<=512 required)
    const int G1   = (E + CH - 1) / CH;     // chunk blocks

    float* ws = (float*)d_ws;
    size_t p = 0;
    auto alloc = [&](size_t elems) { size_t o = p; p += (elems + 63) & ~63ull; return o; };
    float* dinv   = ws + alloc(n);
    int*   rowptr = (int*)(ws + alloc((size_t)n + 1));
    int*   btot   = (int*)(ws + alloc(NBKT));
    int*   bbase  = (int*)(ws + alloc(NBKT));
    int2*  csr    = (int2*)(ws + alloc((size_t)E * 2));
    float* t1     = ws + alloc((size_t)n * 64);            // Â z (f32)
    uint2* zs     = (uint2*)(ws + alloc((size_t)n * 32));  // bf16 pre-scaled operand
    // region X: tmp + hist (preprocessing), then h (dense path) — tmp dead by then
    float* X      = ws + alloc((size_t)n * 128);
    int2*  tmp    = (int2*)X;                       // E int2
    int*   hist   = (int*)(X + (size_t)E * 2);      // NBKT*G1 ints
    float* h      = X;
    (void)ws_size;

    // ---- preprocessing: counting sort by dst, zero global atomics ----
    hist_kernel<<<G1, 256, 0, stream>>>(dst, hist, E, G1, NBKT);
    bscan_kernel<<<NBKT, 64, 0, stream>>>(hist, btot, G1);
    tscan_kernel<<<1, 512, 0, stream>>>(btot, bbase, NBKT);
    scatter_kernel<<<G1, 256, 0, stream>>>(src, dst, ea, hist, bbase, tmp, E, G1, NBKT);
    finalize_kernel<<<NBKT, 256, 0, stream>>>(tmp, bbase, btot, z, rowptr, dinv,
                                              csr, zs, n, E);

    const int gblocks = (n + 3) / 4;
    // ---- layer 1: t1 = Â z ; h = relu(t1 @ W1 + b1) ----
    gaggb_kernel<false><<<gblocks, 256, 0, stream>>>(rowptr, csr, dinv, zs,
                                                     nullptr, t1, n);
    matmulE_kernel<64, 128, true, true, false><<<(n + 7) / 8, 256, 0, stream>>>(
        t1, W1, b1, nullptr, h, n);

    // ---- layer 2: hs = bf16(dinv*(h @ W2)) (reuses zs) ; out = Â hs + b2 ----
    matmulE_kernel<128, 64, false, false, true><<<(n + 15) / 16, 256, 0, stream>>>(
        h, W2, nullptr, dinv, zs, n);
    gaggb_kernel<true><<<gblocks, 256, 0, stream>>>(rowptr, csr, dinv, zs,
                                                    b2, out, n);
}

// Round 14
// 158.180 us; speedup vs baseline: 1.7513x; 1.1244x over previous
//
#include <hip/hip_runtime.h>

// 2-layer GCN, CSR-gather formulation, v14 (= v13 with the t1b allocation bug fixed).
//   Â = D^{-1/2}(A+I)D^{-1/2},  out = Â(relu(Â z W1 + b1))W2 + b2
// layer1: t1b = bf16(Â z); dense: hs = bf16(dinv*(relu(t1b@W1+b1)@W2)) in ONE
// MFMA kernel; layer2: out = gather(hs) + b2.
// v6: CSR via two-level LDS counting sort — zero global atomics.
// v7: bf16 gather operand, 128B row/request. v9: operand pre-scaled by dinv.
// v11: convs fused into finalize; plain (cached) CSR loads.
// v13: dense path on matrix cores (VALU matmuls were LDS-issue bound ~60us).
// v14: FIX v13's t1b alloc (was n*16 floats = half the needed 6.4MB -> t1b
// overlapped zs: gagg1 corrupted its own operand; absmax 0.058).

#define NPB 128   // nodes per fine bucket (dst & 127 is the in-bucket id)
#define CH  4096  // edges per chunk block in hist/scatter passes

typedef __attribute__((ext_vector_type(8))) short short8v;
typedef __attribute__((ext_vector_type(4))) float f32x4;

__device__ __forceinline__ float4 ld4(const float* p) {
    return *reinterpret_cast<const float4*>(p);
}

// round-to-nearest-even f32 -> bf16 (as ushort in low bits)
__device__ __forceinline__ unsigned bfr(float f) {
    unsigned u = __float_as_uint(f);
    return (u + 0x7FFFu + ((u >> 16) & 1u)) >> 16;
}
// unpack 4 bf16 (uint2) -> 4 f32
__device__ __forceinline__ void bf4(uint2 v, float& f0, float& f1, float& f2, float& f3) {
    f0 = __uint_as_float(v.x << 16);
    f1 = __uint_as_float(v.x & 0xFFFF0000u);
    f2 = __uint_as_float(v.y << 16);
    f3 = __uint_as_float(v.y & 0xFFFF0000u);
}

// ---- K0: weight prep: W1T[c][k] (128x64), W2T[c][k] (64x128), both bf16 ----
__global__ __launch_bounds__(256) void prep_kernel(const float* __restrict__ W1,
                                                   const float* __restrict__ W2,
                                                   unsigned short* __restrict__ W1T,
                                                   unsigned short* __restrict__ W2T) {
    for (int i = threadIdx.x; i < 128 * 64; i += 256) {
        int c = i >> 6, k = i & 63;
        W1T[i] = (unsigned short)bfr(W1[k * 128 + c]);
    }
    for (int i = threadIdx.x; i < 64 * 128; i += 256) {
        int c = i >> 7, k = i & 127;
        W2T[i] = (unsigned short)bfr(W2[k * 64 + c]);
    }
}

// ---- K1: coarse histogram per chunk (LDS), bucket-major out: hist[b*G1+g] ----
__global__ __launch_bounds__(256) void hist_kernel(const int* __restrict__ dst,
                                                   int* __restrict__ hist,
                                                   int E, int G1, int NBKT) {
    __shared__ int lh[512];
    for (int i = threadIdx.x; i < NBKT; i += 256) lh[i] = 0;
    __syncthreads();
    int g = blockIdx.x;
    int beg = g * CH, end = min(beg + CH, E);
    for (int j = beg + (int)threadIdx.x; j < end; j += 256)
        atomicAdd(&lh[dst[j] / NPB], 1);
    __syncthreads();
    for (int i = threadIdx.x; i < NBKT; i += 256) hist[(size_t)i * G1 + g] = lh[i];
}

// ---- K2a: per-bucket exclusive scan across chunks (in place); btot[b] = total ----
__global__ __launch_bounds__(64) void bscan_kernel(int* __restrict__ hist,
                                                   int* __restrict__ btot, int G1) {
    int b = blockIdx.x;
    int* row = hist + (size_t)b * G1;
    int lane = threadIdx.x;
    int carry = 0;
    for (int g0 = 0; g0 < G1; g0 += 64) {
        int g = g0 + lane;
        int v = (g < G1) ? row[g] : 0;
        int incl = v;
#pragma unroll
        for (int off = 1; off < 64; off <<= 1) {
            int u = __shfl_up(incl, off, 64);
            if (lane >= off) incl += u;
        }
        if (g < G1) row[g] = carry + incl - v;
        carry += __shfl(incl, 63, 64);
    }
    if (lane == 0) btot[b] = carry;
}

// ---- K2b: exclusive scan of bucket totals -> bucket bases (NBKT <= 512) ----
__global__ __launch_bounds__(512) void tscan_kernel(const int* __restrict__ btot,
                                                    int* __restrict__ bbase, int NBKT) {
    __shared__ int ws[8];
    int t = threadIdx.x;
    int v = (t < NBKT) ? btot[t] : 0;
    int lane = t & 63, wid = t >> 6;
    int incl = v;
#pragma unroll
    for (int off = 1; off < 64; off <<= 1) {
        int u = __shfl_up(incl, off, 64);
        if (lane >= off) incl += u;
    }
    if (lane == 63) ws[wid] = incl;
    __syncthreads();
    int woff = 0;
#pragma unroll
    for (int w = 0; w < 8; ++w) if (w < wid) woff += ws[w];
    if (t < NBKT) bbase[t] = woff + incl - v;
}

// ---- K3: scatter edges into bucket-grouped tmp via LDS cursors ----
__global__ __launch_bounds__(256) void scatter_kernel(const int* __restrict__ src,
                                                      const int* __restrict__ dst,
                                                      const float* __restrict__ ew,
                                                      const int* __restrict__ hist,
                                                      const int* __restrict__ bbase,
                                                      int2* __restrict__ tmp,
                                                      int E, int G1, int NBKT) {
    __shared__ int cursor[512];
    int g = blockIdx.x;
    for (int i = threadIdx.x; i < NBKT; i += 256)
        cursor[i] = bbase[i] + hist[(size_t)i * G1 + g];
    __syncthreads();
    int beg = g * CH, end = min(beg + CH, E);
    for (int j = beg + (int)threadIdx.x; j < end; j += 256) {
        int d = dst[j];
        int b = d / NPB;
        int pos = atomicAdd(&cursor[b], 1);
        tmp[pos] = make_int2(((d & (NPB - 1)) << 24) | src[j], __float_as_int(ew[j]));
    }
}

// ---- K4: per-bucket finalize: rowptr, dinv, final CSR {src, ew}, zs rows ----
__global__ __launch_bounds__(256) void finalize_kernel(const int2* __restrict__ tmp,
                                                       const int* __restrict__ bbase,
                                                       const int* __restrict__ btot,
                                                       const float* __restrict__ z,
                                                       int* __restrict__ rowptr,
                                                       float* __restrict__ dinv,
                                                       int2* __restrict__ csr,
                                                       uint2* __restrict__ zs,
                                                       int n, int E) {
    __shared__ unsigned int hist[NPB];
    __shared__ float dvl[NPB];
    __shared__ int wsum_[2];
    int b = blockIdx.x;
    int base = bbase[b];
    int cnt  = btot[b];
    int tid  = threadIdx.x;
    if (tid < NPB) hist[tid] = 0;
    __syncthreads();
    // phase A: packed count + weighted degree
    for (int j = tid; j < cnt; j += 256) {
        int2 t = tmp[base + j];
        unsigned dlow = ((unsigned)t.x) >> 24;
        unsigned wfix = (unsigned)(__int_as_float(t.y) * 16384.0f);
        atomicAdd(&hist[dlow], (1u << 24) | wfix);
    }
    __syncthreads();
    int c = 0, incl = 0;
    unsigned pk = 0;
    if (tid < NPB) {
        pk = hist[tid];
        c = (int)(pk >> 24);
        incl = c;
#pragma unroll
        for (int off = 1; off < 64; off <<= 1) {
            int u = __shfl_up(incl, off, 64);
            if ((tid & 63) >= off) incl += u;
        }
        if ((tid & 63) == 63) wsum_[tid >> 6] = incl;
    }
    __syncthreads();
    if (tid < NPB) {
        int woff = (tid >= 64) ? wsum_[0] : 0;
        int excl = woff + incl - c;
        int node = b * NPB + tid;
        float dv = 0.f;
        if (node < n) {
            rowptr[node] = base + excl;
            float wdeg = (float)(pk & 0xFFFFFFu) * (1.0f / 16384.0f);
            dv = rsqrtf(wdeg + 1.0f);
            dinv[node] = dv;
        }
        dvl[tid]  = dv;
        hist[tid] = (unsigned)excl;   // becomes cursor for phase B
    }
    if (b == 0 && tid == 0) rowptr[n] = E;
    __syncthreads();
    // phase B: place edges within bucket
    for (int j = tid; j < cnt; j += 256) {
        int2 t = tmp[base + j];
        unsigned dlow = ((unsigned)t.x) >> 24;
        int srcv = t.x & 0xFFFFFF;
        int lr = (int)atomicAdd(&hist[dlow], 1u);
        csr[base + lr] = make_int2(srcv, t.y);
    }
    // phase C (fused convs): zs[node] = bf16(dinv*z[node]) for this block's nodes
    for (int t = tid; t < NPB * 16; t += 256) {
        int li = t >> 4;
        int node = b * NPB + li;
        if (node < n) {
            int k = t & 15;
            float dv = dvl[li];
            float4 f = ld4(z + (size_t)node * 64 + k * 4);
            zs[(size_t)node * 16 + k] =
                make_uint2(bfr(dv * f.x) | (bfr(dv * f.y) << 16),
                           bfr(dv * f.z) | (bfr(dv * f.w) << 16));
        }
    }
}

// ---- gather-aggregate (F=64, bf16 pre-scaled operand): one wave per dst row ----
// Lane l: eg = l>>4 (edge subgroup), fq = l&15 (feature uint2 = 4 bf16).
// out[row] = (BIAS? b : 0) + dv * ( sum_j ew_j * Hp[src_j] + Hp[row] )
// OUTB: write result as bf16 [n][64] (uint2 per lane) instead of f32.
template<bool BIAS, bool OUTB>
__global__ __launch_bounds__(256) void gaggb_kernel(const int* __restrict__ rowptr,
                                                    const int2* __restrict__ csr,
                                                    const float* __restrict__ dinv,
                                                    const uint2* __restrict__ Hp,
                                                    const float* __restrict__ b,
                                                    void* __restrict__ out, int n) {
    int row  = (blockIdx.x * 256 + threadIdx.x) >> 6;
    int lane = threadIdx.x & 63;
    if (row >= n) return;
    int eg = lane >> 4, fq = lane & 15;
    int beg = rowptr[row], end = rowptr[row + 1];
    float dv = dinv[row];

    float ax = 0.f, ay = 0.f, az = 0.f, aw = 0.f;
    float f0, f1, f2, f3;
    int j = beg;
    for (; j + 16 <= end; j += 16) {
        int2 m0 = csr[j + eg];
        int2 m1 = csr[j + eg + 4];
        int2 m2 = csr[j + eg + 8];
        int2 m3 = csr[j + eg + 12];
        uint2 v0 = Hp[(size_t)(unsigned)(m0.x) * 16 + fq];
        uint2 v1 = Hp[(size_t)(unsigned)(m1.x) * 16 + fq];
        uint2 v2 = Hp[(size_t)(unsigned)(m2.x) * 16 + fq];
        uint2 v3 = Hp[(size_t)(unsigned)(m3.x) * 16 + fq];
        float w0 = __int_as_float(m0.y), w1 = __int_as_float(m1.y);
        float w2 = __int_as_float(m2.y), w3 = __int_as_float(m3.y);
        bf4(v0, f0, f1, f2, f3);
        ax += w0 * f0; ay += w0 * f1; az += w0 * f2; aw += w0 * f3;
        bf4(v1, f0, f1, f2, f3);
        ax += w1 * f0; ay += w1 * f1; az += w1 * f2; aw += w1 * f3;
        bf4(v2, f0, f1, f2, f3);
        ax += w2 * f0; ay += w2 * f1; az += w2 * f2; aw += w2 * f3;
        bf4(v3, f0, f1, f2, f3);
        ax += w3 * f0; ay += w3 * f1; az += w3 * f2; aw += w3 * f3;
    }
    for (; j + 4 <= end; j += 4) {
        int2 m0 = csr[j + eg];
        float w0 = __int_as_float(m0.y);
        uint2 v0 = Hp[(size_t)(unsigned)(m0.x) * 16 + fq];
        bf4(v0, f0, f1, f2, f3);
        ax += w0 * f0; ay += w0 * f1; az += w0 * f2; aw += w0 * f3;
    }
    if (j < end) {
        int idx = j + eg;
        if (idx < end) {
            int2 m0 = csr[idx];
            float w0 = __int_as_float(m0.y);
            uint2 v0 = Hp[(size_t)(unsigned)(m0.x) * 16 + fq];
            bf4(v0, f0, f1, f2, f3);
            ax += w0 * f0; ay += w0 * f1; az += w0 * f2; aw += w0 * f3;
        }
    }
    // combine the 4 edge subgroups (lane bits 4,5)
    ax += __shfl_xor(ax, 16, 64); ay += __shfl_xor(ay, 16, 64);
    az += __shfl_xor(az, 16, 64); aw += __shfl_xor(aw, 16, 64);
    ax += __shfl_xor(ax, 32, 64); ay += __shfl_xor(ay, 32, 64);
    az += __shfl_xor(az, 32, 64); aw += __shfl_xor(aw, 32, 64);

    if (eg == 0) {
        uint2 sv = Hp[(size_t)row * 16 + fq];   // self term (already dinv-scaled)
        float s0, s1, s2, s3;
        bf4(sv, s0, s1, s2, s3);
        float4 o;
        o.x = dv * (ax + s0);
        o.y = dv * (ay + s1);
        o.z = dv * (az + s2);
        o.w = dv * (aw + s3);
        if (BIAS) {
            float4 bb = ld4(b + fq * 4);
            o.x += bb.x; o.y += bb.y; o.z += bb.z; o.w += bb.w;
        }
        if (OUTB) {
            uint2 pv = make_uint2(bfr(o.x) | (bfr(o.y) << 16),
                                  bfr(o.z) | (bfr(o.w) << 16));
            reinterpret_cast<uint2*>(out)[(size_t)row * 16 + fq] = pv;
        } else {
            reinterpret_cast<float4*>(out)[(size_t)row * 16 + fq] = o;
        }
    }
}

// ---- fused dense on matrix cores ----
// hs = bf16(dinv * (relu(t1b @ W1 + b1) @ W2)); 64 rows/block (4 waves x 16).
// MFMA 16x16x32 bf16 layouts: A-frag lane l: row=l&15, k=8*(l>>4)+i; B-frag:
// col=l&15, same k mapping (any consistent K-permutation cancels between A and
// B); C/D (verified m89): col=lane&15, row=4*(lane>>4)+reg.
__global__ __launch_bounds__(256) void densemfma_kernel(
        const unsigned short* __restrict__ t1b,   // [n][64] bf16
        const unsigned short* __restrict__ W1T,   // [128][64] bf16 (col-major W1)
        const float* __restrict__ b1,
        const unsigned short* __restrict__ W2T,   // [64][128] bf16 (col-major W2)
        const float* __restrict__ dinv,
        unsigned short* __restrict__ hs,          // [n][64] bf16 out
        int n) {
    __shared__ __align__(16) unsigned short hT[4][16][136];   // 17.4 KB
    int wv = threadIdx.x >> 6;
    int l  = threadIdx.x & 63;
    int m  = l & 15, g = l >> 4;
    int R  = blockIdx.x * 64 + wv * 16;

    // ---- stage 1: C1 = t1b @ W1 (16 x 128), bias+relu -> hT tile (bf16) ----
    short8v a0 = {0,0,0,0,0,0,0,0}, a1 = {0,0,0,0,0,0,0,0};
    int rowA = R + m;
    if (rowA < n) {
        a0 = *reinterpret_cast<const short8v*>(t1b + (size_t)rowA * 64 + 8 * g);
        a1 = *reinterpret_cast<const short8v*>(t1b + (size_t)rowA * 64 + 32 + 8 * g);
    }
#pragma unroll
    for (int ct = 0; ct < 8; ++ct) {
        const unsigned short* wp = W1T + (size_t)(ct * 16 + m) * 64 + 8 * g;
        short8v wb0 = *reinterpret_cast<const short8v*>(wp);
        short8v wb1 = *reinterpret_cast<const short8v*>(wp + 32);
        f32x4 c = {0.f, 0.f, 0.f, 0.f};
        c = __builtin_amdgcn_mfma_f32_16x16x32_bf16(a0, wb0, c, 0, 0, 0);
        c = __builtin_amdgcn_mfma_f32_16x16x32_bf16(a1, wb1, c, 0, 0, 0);
        float bb = b1[ct * 16 + m];
#pragma unroll
        for (int r = 0; r < 4; ++r) {
            float v = fmaxf(c[r] + bb, 0.f);
            hT[wv][4 * g + r][ct * 16 + m] = (unsigned short)bfr(v);
        }
    }
    __syncthreads();

    // ---- stage 2: C2 = hT @ W2 (16 x 64) ----
    f32x4 acc2[4];
#pragma unroll
    for (int ct = 0; ct < 4; ++ct) acc2[ct] = (f32x4){0.f, 0.f, 0.f, 0.f};
#pragma unroll
    for (int kk = 0; kk < 4; ++kk) {
        short8v ha = *reinterpret_cast<const short8v*>(&hT[wv][m][kk * 32 + 8 * g]);
#pragma unroll
        for (int ct = 0; ct < 4; ++ct) {
            short8v wb = *reinterpret_cast<const short8v*>(
                W2T + (size_t)(ct * 16 + m) * 128 + kk * 32 + 8 * g);
            acc2[ct] = __builtin_amdgcn_mfma_f32_16x16x32_bf16(ha, wb, acc2[ct], 0, 0, 0);
        }
    }
    __syncthreads();   // all stage-2 LDS reads done before tile reuse

    // ---- epilogue: scale rows by dinv, bf16, transpose via LDS, store ----
#pragma unroll
    for (int r = 0; r < 4; ++r) {
        int grow = R + 4 * g + r;
        float dv = (grow < n) ? dinv[grow] : 0.f;
#pragma unroll
        for (int ct = 0; ct < 4; ++ct)
            hT[wv][4 * g + r][ct * 16 + m] = (unsigned short)bfr(acc2[ct][r] * dv);
    }
    __syncthreads();
    int growO = R + m;
    if (growO < n) {
        uint4 u0 = *reinterpret_cast<const uint4*>(&hT[wv][m][g * 16]);
        uint4 u1 = *reinterpret_cast<const uint4*>(&hT[wv][m][g * 16 + 8]);
        *reinterpret_cast<uint4*>(hs + (size_t)growO * 64 + g * 16) = u0;
        *reinterpret_cast<uint4*>(hs + (size_t)growO * 64 + g * 16 + 8) = u1;
    }
}

extern "C" void kernel_launch(void* const* d_in, const int* in_sizes, int n_in,
                              void* d_out, int out_size, void* d_ws, size_t ws_size,
                              hipStream_t stream) {
    const float* z  = (const float*)d_in[0];
    const int*   ei = (const int*)d_in[1];
    const float* ea = (const float*)d_in[2];
    const float* W1 = (const float*)d_in[3];
    const float* b1 = (const float*)d_in[4];
    const float* W2 = (const float*)d_in[5];
    const float* b2 = (const float*)d_in[6];
    float* out = (float*)d_out;

    const int n = in_sizes[0] / 64;   // LAT = 64
    const int E = in_sizes[2];
    const int* src = ei;
    const int* dst = ei + E;
    const int NBKT = (n + NPB - 1) / NPB;   // 391 for n=50000 (<=512 required)
    const int G1   = (E + CH - 1) / CH;     // chunk blocks

    float* ws = (float*)d_ws;
    size_t p = 0;
    auto alloc = [&](size_t elems) { size_t o = p; p += (elems + 63) & ~63ull; return o; };
    float* dinv   = ws + alloc(n);
    int*   rowptr = (int*)(ws + alloc((size_t)n + 1));
    int*   btot   = (int*)(ws + alloc(NBKT));
    int*   bbase  = (int*)(ws + alloc(NBKT));
    int2*  csr    = (int2*)(ws + alloc((size_t)E * 2));
    unsigned short* t1b = (unsigned short*)(ws + alloc((size_t)n * 32)); // [n][64] bf16 (n*128 B)
    uint2* zs     = (uint2*)(ws + alloc((size_t)n * 32));  // bf16 operand / hs
    unsigned short* W1T = (unsigned short*)(ws + alloc(4096));  // 128x64 bf16
    unsigned short* W2T = (unsigned short*)(ws + alloc(4096));  // 64x128 bf16
    // region X: tmp + hist (preprocessing only)
    float* X      = ws + alloc((size_t)E * 2 + (size_t)NBKT * G1 + 64);
    int2*  tmp    = (int2*)X;                       // E int2
    int*   hist   = (int*)(X + (size_t)E * 2);      // NBKT*G1 ints
    (void)ws_size;

    // ---- preprocessing: weight prep + counting sort by dst ----
    prep_kernel<<<1, 256, 0, stream>>>(W1, W2, W1T, W2T);
    hist_kernel<<<G1, 256, 0, stream>>>(dst, hist, E, G1, NBKT);
    bscan_kernel<<<NBKT, 64, 0, stream>>>(hist, btot, G1);
    tscan_kernel<<<1, 512, 0, stream>>>(btot, bbase, NBKT);
    scatter_kernel<<<G1, 256, 0, stream>>>(src, dst, ea, hist, bbase, tmp, E, G1, NBKT);
    finalize_kernel<<<NBKT, 256, 0, stream>>>(tmp, bbase, btot, z, rowptr, dinv,
                                              csr, zs, n, E);

    const int gblocks = (n + 3) / 4;
    // ---- layer 1 gather: t1b = bf16(Â z) ----
    gaggb_kernel<false, true><<<gblocks, 256, 0, stream>>>(rowptr, csr, dinv, zs,
                                                           nullptr, t1b, n);
    // ---- fused dense on MFMA: hs = bf16(dinv*(relu(t1b@W1+b1)@W2)) (reuses zs) ----
    densemfma_kernel<<<(n + 63) / 64, 256, 0, stream>>>(t1b, W1T, b1, W2T, dinv,
                                                        (unsigned short*)zs, n);
    // ---- layer 2 gather: out = Â hs + b2 ----
    gaggb_kernel<true, false><<<gblocks, 256, 0, stream>>>(rowptr, csr, dinv, zs,
                                                           b2, out, n);
}

// Round 15
// 149.559 us; speedup vs baseline: 1.8523x; 1.0576x over previous
//
#include <hip/hip_runtime.h>

// 2-layer GCN, CSR-gather formulation, v15.
//   Â = D^{-1/2}(A+I)D^{-1/2},  out = Â(relu(Â z W1 + b1))W2 + b2
// layer1: t1b = bf16(Â z); dense: hs = bf16(dinv*(relu(t1b@W1+b1)@W2)) on MFMA;
// layer2: out = gather(hs) + b2.
// v6: CSR via counting sort — zero global atomics. v7: bf16 gather operand.
// v9: operand pre-scaled by dinv. v11: convs fused into finalize.
// v13/14: dense on matrix cores. v15: gagg 32-edge unroll (R10 showed
// latency*MLP bound; deg~32 so 16-deep left half the row unissued);
// densemfma stages bf16 weights in padded LDS (no prep kernel, no inner
// barriers — hT slices are wave-local); tscan folded into scatter/finalize.

#define NPB 128   // nodes per fine bucket (dst & 127 is the in-bucket id)
#define CH  4096  // edges per chunk block in hist/scatter passes

typedef __attribute__((ext_vector_type(8))) short short8v;
typedef __attribute__((ext_vector_type(4))) float f32x4;

__device__ __forceinline__ float4 ld4(const float* p) {
    return *reinterpret_cast<const float4*>(p);
}

// round-to-nearest-even f32 -> bf16 (as ushort in low bits)
__device__ __forceinline__ unsigned bfr(float f) {
    unsigned u = __float_as_uint(f);
    return (u + 0x7FFFu + ((u >> 16) & 1u)) >> 16;
}
// unpack 4 bf16 (uint2) -> 4 f32
__device__ __forceinline__ void bf4(uint2 v, float& f0, float& f1, float& f2, float& f3) {
    f0 = __uint_as_float(v.x << 16);
    f1 = __uint_as_float(v.x & 0xFFFF0000u);
    f2 = __uint_as_float(v.y << 16);
    f3 = __uint_as_float(v.y & 0xFFFF0000u);
}

// exclusive scan of btot[0..NBKT) into LDS bbs[] (blockDim=256, NBKT<=512)
__device__ __forceinline__ void scan_btot(const int* __restrict__ btot, int NBKT,
                                          int* bbs, int* wtot) {
    int tid = threadIdx.x;
    int v0 = (2 * tid     < NBKT) ? btot[2 * tid]     : 0;
    int v1 = (2 * tid + 1 < NBKT) ? btot[2 * tid + 1] : 0;
    int s = v0 + v1;
    int lane = tid & 63, wid = tid >> 6;
    int incl = s;
#pragma unroll
    for (int off = 1; off < 64; off <<= 1) {
        int u = __shfl_up(incl, off, 64);
        if (lane >= off) incl += u;
    }
    if (lane == 63) wtot[wid] = incl;
    __syncthreads();
    int woff = 0;
#pragma unroll
    for (int w = 0; w < 4; ++w) if (w < wid) woff += wtot[w];
    int ex = woff + incl - s;
    if (2 * tid     < NBKT) bbs[2 * tid]     = ex;
    if (2 * tid + 1 < NBKT) bbs[2 * tid + 1] = ex + v0;
    __syncthreads();
}

// ---- K1: coarse histogram per chunk (LDS), bucket-major out: hist[b*G1+g] ----
__global__ __launch_bounds__(256) void hist_kernel(const int* __restrict__ dst,
                                                   int* __restrict__ hist,
                                                   int E, int G1, int NBKT) {
    __shared__ int lh[512];
    for (int i = threadIdx.x; i < NBKT; i += 256) lh[i] = 0;
    __syncthreads();
    int g = blockIdx.x;
    int beg = g * CH, end = min(beg + CH, E);
    for (int j = beg + (int)threadIdx.x; j < end; j += 256)
        atomicAdd(&lh[dst[j] / NPB], 1);
    __syncthreads();
    for (int i = threadIdx.x; i < NBKT; i += 256) hist[(size_t)i * G1 + g] = lh[i];
}

// ---- K2: per-bucket exclusive scan across chunks (in place); btot[b] = total ----
__global__ __launch_bounds__(64) void bscan_kernel(int* __restrict__ hist,
                                                   int* __restrict__ btot, int G1) {
    int b = blockIdx.x;
    int* row = hist + (size_t)b * G1;
    int lane = threadIdx.x;
    int carry = 0;
    for (int g0 = 0; g0 < G1; g0 += 64) {
        int g = g0 + lane;
        int v = (g < G1) ? row[g] : 0;
        int incl = v;
#pragma unroll
        for (int off = 1; off < 64; off <<= 1) {
            int u = __shfl_up(incl, off, 64);
            if (lane >= off) incl += u;
        }
        if (g < G1) row[g] = carry + incl - v;
        carry += __shfl(incl, 63, 64);
    }
    if (lane == 0) btot[b] = carry;
}

// ---- K3: scatter edges into bucket-grouped tmp via LDS cursors (scan fused) ----
__global__ __launch_bounds__(256) void scatter_kernel(const int* __restrict__ src,
                                                      const int* __restrict__ dst,
                                                      const float* __restrict__ ew,
                                                      const int* __restrict__ hist,
                                                      const int* __restrict__ btot,
                                                      int2* __restrict__ tmp,
                                                      int E, int G1, int NBKT) {
    __shared__ int bbs[512];
    __shared__ int wtot[4];
    __shared__ int cursor[512];
    scan_btot(btot, NBKT, bbs, wtot);
    int g = blockIdx.x;
    for (int i = threadIdx.x; i < NBKT; i += 256)
        cursor[i] = bbs[i] + hist[(size_t)i * G1 + g];
    __syncthreads();
    int beg = g * CH, end = min(beg + CH, E);
    for (int j = beg + (int)threadIdx.x; j < end; j += 256) {
        int d = dst[j];
        int b = d / NPB;
        int pos = atomicAdd(&cursor[b], 1);
        tmp[pos] = make_int2(((d & (NPB - 1)) << 24) | src[j], __float_as_int(ew[j]));
    }
}

// ---- K4: per-bucket finalize: rowptr, dinv, final CSR {src, ew}, zs rows ----
__global__ __launch_bounds__(256) void finalize_kernel(const int2* __restrict__ tmp,
                                                       const int* __restrict__ btot,
                                                       const float* __restrict__ z,
                                                       int* __restrict__ rowptr,
                                                       float* __restrict__ dinv,
                                                       int2* __restrict__ csr,
                                                       uint2* __restrict__ zs,
                                                       int n, int E, int NBKT) {
    __shared__ int bbs[512];
    __shared__ int wsum_[4];
    __shared__ unsigned int hist[NPB];
    __shared__ float dvl[NPB];
    scan_btot(btot, NBKT, bbs, wsum_);
    int b = blockIdx.x;
    int base = bbs[b];
    int cnt  = btot[b];
    int tid  = threadIdx.x;
    if (tid < NPB) hist[tid] = 0;
    __syncthreads();
    // phase A: packed count + weighted degree
    for (int j = tid; j < cnt; j += 256) {
        int2 t = tmp[base + j];
        unsigned dlow = ((unsigned)t.x) >> 24;
        unsigned wfix = (unsigned)(__int_as_float(t.y) * 16384.0f);
        atomicAdd(&hist[dlow], (1u << 24) | wfix);
    }
    __syncthreads();
    int c = 0, incl = 0;
    unsigned pk = 0;
    if (tid < NPB) {
        pk = hist[tid];
        c = (int)(pk >> 24);
        incl = c;
#pragma unroll
        for (int off = 1; off < 64; off <<= 1) {
            int u = __shfl_up(incl, off, 64);
            if ((tid & 63) >= off) incl += u;
        }
        if ((tid & 63) == 63) wsum_[tid >> 6] = incl;
    }
    __syncthreads();
    if (tid < NPB) {
        int woff = (tid >= 64) ? wsum_[0] : 0;
        int excl = woff + incl - c;
        int node = b * NPB + tid;
        float dv = 0.f;
        if (node < n) {
            rowptr[node] = base + excl;
            float wdeg = (float)(pk & 0xFFFFFFu) * (1.0f / 16384.0f);
            dv = rsqrtf(wdeg + 1.0f);
            dinv[node] = dv;
        }
        dvl[tid]  = dv;
        hist[tid] = (unsigned)excl;   // becomes cursor for phase B
    }
    if (b == 0 && tid == 0) rowptr[n] = E;
    __syncthreads();
    // phase B: place edges within bucket
    for (int j = tid; j < cnt; j += 256) {
        int2 t = tmp[base + j];
        unsigned dlow = ((unsigned)t.x) >> 24;
        int srcv = t.x & 0xFFFFFF;
        int lr = (int)atomicAdd(&hist[dlow], 1u);
        csr[base + lr] = make_int2(srcv, t.y);
    }
    // phase C (fused convs): zs[node] = bf16(dinv*z[node]) for this block's nodes
    for (int t = tid; t < NPB * 16; t += 256) {
        int li = t >> 4;
        int node = b * NPB + li;
        if (node < n) {
            int k = t & 15;
            float dv = dvl[li];
            float4 f = ld4(z + (size_t)node * 64 + k * 4);
            zs[(size_t)node * 16 + k] =
                make_uint2(bfr(dv * f.x) | (bfr(dv * f.y) << 16),
                           bfr(dv * f.z) | (bfr(dv * f.w) << 16));
        }
    }
}

// ---- gather-aggregate (F=64, bf16 pre-scaled operand): one wave per dst row ----
// Lane l: eg = l>>4 (edge subgroup), fq = l&15 (feature uint2 = 4 bf16).
// out[row] = (BIAS? b : 0) + dv * ( sum_j ew_j * Hp[src_j] + Hp[row] )
// OUTB: write result as bf16 [n][64] (uint2 per lane) instead of f32.
template<bool BIAS, bool OUTB>
__global__ __launch_bounds__(256) void gaggb_kernel(const int* __restrict__ rowptr,
                                                    const int2* __restrict__ csr,
                                                    const float* __restrict__ dinv,
                                                    const uint2* __restrict__ Hp,
                                                    const float* __restrict__ b,
                                                    void* __restrict__ out, int n) {
    int row  = (blockIdx.x * 256 + threadIdx.x) >> 6;
    int lane = threadIdx.x & 63;
    if (row >= n) return;
    int eg = lane >> 4, fq = lane & 15;
    int beg = rowptr[row], end = rowptr[row + 1];
    float dv = dinv[row];

    float ax = 0.f, ay = 0.f, az = 0.f, aw = 0.f;
    float f0, f1, f2, f3;
    int j = beg;
    // 32 edges in flight (8 csr loads + 8 row gathers per subgroup pass)
    for (; j + 32 <= end; j += 32) {
        int2 m0 = csr[j + eg];
        int2 m1 = csr[j + eg + 4];
        int2 m2 = csr[j + eg + 8];
        int2 m3 = csr[j + eg + 12];
        int2 m4 = csr[j + eg + 16];
        int2 m5 = csr[j + eg + 20];
        int2 m6 = csr[j + eg + 24];
        int2 m7 = csr[j + eg + 28];
        uint2 v0 = Hp[(size_t)(unsigned)(m0.x) * 16 + fq];
        uint2 v1 = Hp[(size_t)(unsigned)(m1.x) * 16 + fq];
        uint2 v2 = Hp[(size_t)(unsigned)(m2.x) * 16 + fq];
        uint2 v3 = Hp[(size_t)(unsigned)(m3.x) * 16 + fq];
        uint2 v4 = Hp[(size_t)(unsigned)(m4.x) * 16 + fq];
        uint2 v5 = Hp[(size_t)(unsigned)(m5.x) * 16 + fq];
        uint2 v6 = Hp[(size_t)(unsigned)(m6.x) * 16 + fq];
        uint2 v7 = Hp[(size_t)(unsigned)(m7.x) * 16 + fq];
        float w0 = __int_as_float(m0.y), w1 = __int_as_float(m1.y);
        float w2 = __int_as_float(m2.y), w3 = __int_as_float(m3.y);
        float w4 = __int_as_float(m4.y), w5 = __int_as_float(m5.y);
        float w6 = __int_as_float(m6.y), w7 = __int_as_float(m7.y);
        bf4(v0, f0, f1, f2, f3);
        ax += w0 * f0; ay += w0 * f1; az += w0 * f2; aw += w0 * f3;
        bf4(v1, f0, f1, f2, f3);
        ax += w1 * f0; ay += w1 * f1; az += w1 * f2; aw += w1 * f3;
        bf4(v2, f0, f1, f2, f3);
        ax += w2 * f0; ay += w2 * f1; az += w2 * f2; aw += w2 * f3;
        bf4(v3, f0, f1, f2, f3);
        ax += w3 * f0; ay += w3 * f1; az += w3 * f2; aw += w3 * f3;
        bf4(v4, f0, f1, f2, f3);
        ax += w4 * f0; ay += w4 * f1; az += w4 * f2; aw += w4 * f3;
        bf4(v5, f0, f1, f2, f3);
        ax += w5 * f0; ay += w5 * f1; az += w5 * f2; aw += w5 * f3;
        bf4(v6, f0, f1, f2, f3);
        ax += w6 * f0; ay += w6 * f1; az += w6 * f2; aw += w6 * f3;
        bf4(v7, f0, f1, f2, f3);
        ax += w7 * f0; ay += w7 * f1; az += w7 * f2; aw += w7 * f3;
    }
    for (; j + 16 <= end; j += 16) {
        int2 m0 = csr[j + eg];
        int2 m1 = csr[j + eg + 4];
        int2 m2 = csr[j + eg + 8];
        int2 m3 = csr[j + eg + 12];
        uint2 v0 = Hp[(size_t)(unsigned)(m0.x) * 16 + fq];
        uint2 v1 = Hp[(size_t)(unsigned)(m1.x) * 16 + fq];
        uint2 v2 = Hp[(size_t)(unsigned)(m2.x) * 16 + fq];
        uint2 v3 = Hp[(size_t)(unsigned)(m3.x) * 16 + fq];
        float w0 = __int_as_float(m0.y), w1 = __int_as_float(m1.y);
        float w2 = __int_as_float(m2.y), w3 = __int_as_float(m3.y);
        bf4(v0, f0, f1, f2, f3);
        ax += w0 * f0; ay += w0 * f1; az += w0 * f2; aw += w0 * f3;
        bf4(v1, f0, f1, f2, f3);
        ax += w1 * f0; ay += w1 * f1; az += w1 * f2; aw += w1 * f3;
        bf4(v2, f0, f1, f2, f3);
        ax += w2 * f0; ay += w2 * f1; az += w2 * f2; aw += w2 * f3;
        bf4(v3, f0, f1, f2, f3);
        ax += w3 * f0; ay += w3 * f1; az += w3 * f2; aw += w3 * f3;
    }
    for (; j + 4 <= end; j += 4) {
        int2 m0 = csr[j + eg];
        float w0 = __int_as_float(m0.y);
        uint2 v0 = Hp[(size_t)(unsigned)(m0.x) * 16 + fq];
        bf4(v0, f0, f1, f2, f3);
        ax += w0 * f0; ay += w0 * f1; az += w0 * f2; aw += w0 * f3;
    }
    if (j < end) {
        int idx = j + eg;
        if (idx < end) {
            int2 m0 = csr[idx];
            float w0 = __int_as_float(m0.y);
            uint2 v0 = Hp[(size_t)(unsigned)(m0.x) * 16 + fq];
            bf4(v0, f0, f1, f2, f3);
            ax += w0 * f0; ay += w0 * f1; az += w0 * f2; aw += w0 * f3;
        }
    }
    // combine the 4 edge subgroups (lane bits 4,5)
    ax += __shfl_xor(ax, 16, 64); ay += __shfl_xor(ay, 16, 64);
    az += __shfl_xor(az, 16, 64); aw += __shfl_xor(aw, 16, 64);
    ax += __shfl_xor(ax, 32, 64); ay += __shfl_xor(ay, 32, 64);
    az += __shfl_xor(az, 32, 64); aw += __shfl_xor(aw, 32, 64);

    if (eg == 0) {
        uint2 sv = Hp[(size_t)row * 16 + fq];   // self term (already dinv-scaled)
        float s0, s1, s2, s3;
        bf4(sv, s0, s1, s2, s3);
        float4 o;
        o.x = dv * (ax + s0);
        o.y = dv * (ay + s1);
        o.z = dv * (az + s2);
        o.w = dv * (aw + s3);
        if (BIAS) {
            float4 bb = ld4(b + fq * 4);
            o.x += bb.x; o.y += bb.y; o.z += bb.z; o.w += bb.w;
        }
        if (OUTB) {
            uint2 pv = make_uint2(bfr(o.x) | (bfr(o.y) << 16),
                                  bfr(o.z) | (bfr(o.w) << 16));
            reinterpret_cast<uint2*>(out)[(size_t)row * 16 + fq] = pv;
        } else {
            reinterpret_cast<float4*>(out)[(size_t)row * 16 + fq] = o;
        }
    }
}

// ---- fused dense on matrix cores (weights staged in padded LDS) ----
// hs = bf16(dinv * (relu(t1b @ W1 + b1) @ W2)); 64 rows per group, 4 waves x 16.
// Grid-strided; weights converted f32->bf16 during staging (no prep kernel).
// hT slices are wave-local -> no inner barriers needed.
__global__ __launch_bounds__(256) void densemfma_kernel(
        const unsigned short* __restrict__ t1b,   // [n][64] bf16
        const float* __restrict__ W1,             // [64][128] f32
        const float* __restrict__ b1,
        const float* __restrict__ W2,             // [128][64] f32
        const float* __restrict__ dinv,
        unsigned short* __restrict__ hs,          // [n][64] bf16 out
        int n) {
    __shared__ __align__(16) unsigned short W1s[128][68];   // [outcol][k], padded
    __shared__ __align__(16) unsigned short W2s[64][132];   // [outcol][k], padded
    __shared__ float b1s[128];
    __shared__ __align__(16) unsigned short hT[4][16][136];
    for (int i = threadIdx.x; i < 128 * 64; i += 256) {
        int c = i >> 6, k = i & 63;
        W1s[c][k] = (unsigned short)bfr(W1[k * 128 + c]);
    }
    for (int i = threadIdx.x; i < 64 * 128; i += 256) {
        int c = i >> 7, k = i & 127;
        W2s[c][k] = (unsigned short)bfr(W2[k * 64 + c]);
    }
    if (threadIdx.x < 128) b1s[threadIdx.x] = b1[threadIdx.x];
    __syncthreads();

    int wv = threadIdx.x >> 6;
    int l  = threadIdx.x & 63;
    int m  = l & 15, g = l >> 4;
    int ngrp = (n + 63) >> 6;
    for (int grp = blockIdx.x; grp < ngrp; grp += gridDim.x) {
        int R = grp * 64 + wv * 16;
        // ---- stage 1: C1 = t1b @ W1 (16 x 128), bias+relu -> hT tile ----
        short8v a0 = {0,0,0,0,0,0,0,0}, a1 = {0,0,0,0,0,0,0,0};
        int rowA = R + m;
        if (rowA < n) {
            a0 = *reinterpret_cast<const short8v*>(t1b + (size_t)rowA * 64 + 8 * g);
            a1 = *reinterpret_cast<const short8v*>(t1b + (size_t)rowA * 64 + 32 + 8 * g);
        }
#pragma unroll
        for (int ct = 0; ct < 8; ++ct) {
            short8v wb0 = *reinterpret_cast<const short8v*>(&W1s[ct * 16 + m][8 * g]);
            short8v wb1 = *reinterpret_cast<const short8v*>(&W1s[ct * 16 + m][32 + 8 * g]);
            f32x4 c = {0.f, 0.f, 0.f, 0.f};
            c = __builtin_amdgcn_mfma_f32_16x16x32_bf16(a0, wb0, c, 0, 0, 0);
            c = __builtin_amdgcn_mfma_f32_16x16x32_bf16(a1, wb1, c, 0, 0, 0);
            float bb = b1s[ct * 16 + m];
#pragma unroll
            for (int r = 0; r < 4; ++r) {
                float v = fmaxf(c[r] + bb, 0.f);
                hT[wv][4 * g + r][ct * 16 + m] = (unsigned short)bfr(v);
            }
        }
        // ---- stage 2: C2 = hT @ W2 (16 x 64); hT slice is wave-local ----
        f32x4 acc2[4];
#pragma unroll
        for (int ct = 0; ct < 4; ++ct) acc2[ct] = (f32x4){0.f, 0.f, 0.f, 0.f};
#pragma unroll
        for (int kk = 0; kk < 4; ++kk) {
            short8v ha = *reinterpret_cast<const short8v*>(&hT[wv][m][kk * 32 + 8 * g]);
#pragma unroll
            for (int ct = 0; ct < 4; ++ct) {
                short8v wb = *reinterpret_cast<const short8v*>(
                    &W2s[ct * 16 + m][kk * 32 + 8 * g]);
                acc2[ct] = __builtin_amdgcn_mfma_f32_16x16x32_bf16(ha, wb, acc2[ct], 0, 0, 0);
            }
        }
        // ---- epilogue: dinv-scale, bf16, transpose via wave-local hT, store ----
#pragma unroll
        for (int r = 0; r < 4; ++r) {
            int grow = R + 4 * g + r;
            float dv = (grow < n) ? dinv[grow] : 0.f;
#pragma unroll
            for (int ct = 0; ct < 4; ++ct)
                hT[wv][4 * g + r][ct * 16 + m] = (unsigned short)bfr(acc2[ct][r] * dv);
        }
        int growO = R + m;
        if (growO < n) {
            uint4 u0 = *reinterpret_cast<const uint4*>(&hT[wv][m][g * 16]);
            uint4 u1 = *reinterpret_cast<const uint4*>(&hT[wv][m][g * 16 + 8]);
            *reinterpret_cast<uint4*>(hs + (size_t)growO * 64 + g * 16) = u0;
            *reinterpret_cast<uint4*>(hs + (size_t)growO * 64 + g * 16 + 8) = u1;
        }
    }
}

extern "C" void kernel_launch(void* const* d_in, const int* in_sizes, int n_in,
                              void* d_out, int out_size, void* d_ws, size_t ws_size,
                              hipStream_t stream) {
    const float* z  = (const float*)d_in[0];
    const int*   ei = (const int*)d_in[1];
    const float* ea = (const float*)d_in[2];
    const float* W1 = (const float*)d_in[3];
    const float* b1 = (const float*)d_in[4];
    const float* W2 = (const float*)d_in[5];
    const float* b2 = (const float*)d_in[6];
    float* out = (float*)d_out;

    const int n = in_sizes[0] / 64;   // LAT = 64
    const int E = in_sizes[2];
    const int* src = ei;
    const int* dst = ei + E;
    const int NBKT = (n + NPB - 1) / NPB;   // 391 for n=50000 (<=512 required)
    const int G1   = (E + CH - 1) / CH;     // chunk blocks

    float* ws = (float*)d_ws;
    size_t p = 0;
    auto alloc = [&](size_t elems) { size_t o = p; p += (elems + 63) & ~63ull; return o; };
    float* dinv   = ws + alloc(n);
    int*   rowptr = (int*)(ws + alloc((size_t)n + 1));
    int*   btot   = (int*)(ws + alloc(NBKT));
    int2*  csr    = (int2*)(ws + alloc((size_t)E * 2));
    unsigned short* t1b = (unsigned short*)(ws + alloc((size_t)n * 32)); // [n][64] bf16
    uint2* zs     = (uint2*)(ws + alloc((size_t)n * 32));  // bf16 operand / hs
    // region X: tmp + hist (preprocessing only)
    float* X      = ws + alloc((size_t)E * 2 + (size_t)NBKT * G1 + 64);
    int2*  tmp    = (int2*)X;                       // E int2
    int*   hist   = (int*)(X + (size_t)E * 2);      // NBKT*G1 ints
    (void)ws_size;

    // ---- preprocessing: counting sort by dst, zero global atomics ----
    hist_kernel<<<G1, 256, 0, stream>>>(dst, hist, E, G1, NBKT);
    bscan_kernel<<<NBKT, 64, 0, stream>>>(hist, btot, G1);
    scatter_kernel<<<G1, 256, 0, stream>>>(src, dst, ea, hist, btot, tmp, E, G1, NBKT);
    finalize_kernel<<<NBKT, 256, 0, stream>>>(tmp, btot, z, rowptr, dinv,
                                              csr, zs, n, E, NBKT);

    const int gblocks = (n + 3) / 4;
    // ---- layer 1 gather: t1b = bf16(Â z) ----
    gaggb_kernel<false, true><<<gblocks, 256, 0, stream>>>(rowptr, csr, dinv, zs,
                                                           nullptr, t1b, n);
    // ---- fused dense on MFMA: hs = bf16(dinv*(relu(t1b@W1+b1)@W2)) (reuses zs) ----
    densemfma_kernel<<<256, 256, 0, stream>>>(t1b, W1, b1, W2, dinv,
                                              (unsigned short*)zs, n);
    // ---- layer 2 gather: out = Â hs + b2 ----
    gaggb_kernel<true, false><<<gblocks, 256, 0, stream>>>(rowptr, csr, dinv, zs,
                                                           b2, out, n);
}

// Round 16
// 146.890 us; speedup vs baseline: 1.8859x; 1.0182x over previous
//
#include <hip/hip_runtime.h>

// 2-layer GCN, CSR-gather formulation, v16.
//   Â = D^{-1/2}(A+I)D^{-1/2},  out = Â(relu(Â z W1 + b1))W2 + b2
// layer1: t1b = bf16(Â z); dense: hs = bf16(dinv*(relu(t1b@W1+b1)@W2)) on MFMA;
// layer2: out = gather(hs) + b2.
// v6: CSR via counting sort — zero global atomics. v7: bf16 gather operand.
// v9: operand pre-scaled by dinv. v11: convs fused into finalize.
// v13/14: dense on matrix cores. v15: 32-edge MLP, fused scans, LDS-staged W.
// v16: gagg lane shape 16x8B -> 8x16B (uint4/lane): 8 edges per wave load
// instruction (2x), same 32-edge depth; CH 4096->8192. Note: gagg HBM fetch
// ~= NXCD * operand + CSR (each XCD L2 pulls the whole 6.4MB operand) — the
// structural floor for random gathers unless operand fits 4MiB.

#define NPB 128   // nodes per fine bucket (dst & 127 is the in-bucket id)
#define CH  8192  // edges per chunk block in hist/scatter passes

typedef __attribute__((ext_vector_type(8))) short short8v;
typedef __attribute__((ext_vector_type(4))) float f32x4;

__device__ __forceinline__ float4 ld4(const float* p) {
    return *reinterpret_cast<const float4*>(p);
}

// round-to-nearest-even f32 -> bf16 (as ushort in low bits)
__device__ __forceinline__ unsigned bfr(float f) {
    unsigned u = __float_as_uint(f);
    return (u + 0x7FFFu + ((u >> 16) & 1u)) >> 16;
}
// unpack uint (2 bf16) -> 2 f32
__device__ __forceinline__ void bf2(unsigned v, float& lo, float& hi) {
    lo = __uint_as_float(v << 16);
    hi = __uint_as_float(v & 0xFFFF0000u);
}

// exclusive scan of btot[0..NBKT) into LDS bbs[] (blockDim=256, NBKT<=512)
__device__ __forceinline__ void scan_btot(const int* __restrict__ btot, int NBKT,
                                          int* bbs, int* wtot) {
    int tid = threadIdx.x;
    int v0 = (2 * tid     < NBKT) ? btot[2 * tid]     : 0;
    int v1 = (2 * tid + 1 < NBKT) ? btot[2 * tid + 1] : 0;
    int s = v0 + v1;
    int lane = tid & 63, wid = tid >> 6;
    int incl = s;
#pragma unroll
    for (int off = 1; off < 64; off <<= 1) {
        int u = __shfl_up(incl, off, 64);
        if (lane >= off) incl += u;
    }
    if (lane == 63) wtot[wid] = incl;
    __syncthreads();
    int woff = 0;
#pragma unroll
    for (int w = 0; w < 4; ++w) if (w < wid) woff += wtot[w];
    int ex = woff + incl - s;
    if (2 * tid     < NBKT) bbs[2 * tid]     = ex;
    if (2 * tid + 1 < NBKT) bbs[2 * tid + 1] = ex + v0;
    __syncthreads();
}

// ---- K1: coarse histogram per chunk (LDS), bucket-major out: hist[b*G1+g] ----
__global__ __launch_bounds__(256) void hist_kernel(const int* __restrict__ dst,
                                                   int* __restrict__ hist,
                                                   int E, int G1, int NBKT) {
    __shared__ int lh[512];
    for (int i = threadIdx.x; i < NBKT; i += 256) lh[i] = 0;
    __syncthreads();
    int g = blockIdx.x;
    int beg = g * CH, end = min(beg + CH, E);
    for (int j = beg + (int)threadIdx.x; j < end; j += 256)
        atomicAdd(&lh[dst[j] / NPB], 1);
    __syncthreads();
    for (int i = threadIdx.x; i < NBKT; i += 256) hist[(size_t)i * G1 + g] = lh[i];
}

// ---- K2: per-bucket exclusive scan across chunks (in place); btot[b] = total ----
__global__ __launch_bounds__(64) void bscan_kernel(int* __restrict__ hist,
                                                   int* __restrict__ btot, int G1) {
    int b = blockIdx.x;
    int* row = hist + (size_t)b * G1;
    int lane = threadIdx.x;
    int carry = 0;
    for (int g0 = 0; g0 < G1; g0 += 64) {
        int g = g0 + lane;
        int v = (g < G1) ? row[g] : 0;
        int incl = v;
#pragma unroll
        for (int off = 1; off < 64; off <<= 1) {
            int u = __shfl_up(incl, off, 64);
            if (lane >= off) incl += u;
        }
        if (g < G1) row[g] = carry + incl - v;
        carry += __shfl(incl, 63, 64);
    }
    if (lane == 0) btot[b] = carry;
}

// ---- K3: scatter edges into bucket-grouped tmp via LDS cursors (scan fused) ----
__global__ __launch_bounds__(256) void scatter_kernel(const int* __restrict__ src,
                                                      const int* __restrict__ dst,
                                                      const float* __restrict__ ew,
                                                      const int* __restrict__ hist,
                                                      const int* __restrict__ btot,
                                                      int2* __restrict__ tmp,
                                                      int E, int G1, int NBKT) {
    __shared__ int bbs[512];
    __shared__ int wtot[4];
    __shared__ int cursor[512];
    scan_btot(btot, NBKT, bbs, wtot);
    int g = blockIdx.x;
    for (int i = threadIdx.x; i < NBKT; i += 256)
        cursor[i] = bbs[i] + hist[(size_t)i * G1 + g];
    __syncthreads();
    int beg = g * CH, end = min(beg + CH, E);
    for (int j = beg + (int)threadIdx.x; j < end; j += 256) {
        int d = dst[j];
        int b = d / NPB;
        int pos = atomicAdd(&cursor[b], 1);
        tmp[pos] = make_int2(((d & (NPB - 1)) << 24) | src[j], __float_as_int(ew[j]));
    }
}

// ---- K4: per-bucket finalize: rowptr, dinv, final CSR {src, ew}, zs rows ----
__global__ __launch_bounds__(256) void finalize_kernel(const int2* __restrict__ tmp,
                                                       const int* __restrict__ btot,
                                                       const float* __restrict__ z,
                                                       int* __restrict__ rowptr,
                                                       float* __restrict__ dinv,
                                                       int2* __restrict__ csr,
                                                       uint2* __restrict__ zs,
                                                       int n, int E, int NBKT) {
    __shared__ int bbs[512];
    __shared__ int wsum_[4];
    __shared__ unsigned int hist[NPB];
    __shared__ float dvl[NPB];
    scan_btot(btot, NBKT, bbs, wsum_);
    int b = blockIdx.x;
    int base = bbs[b];
    int cnt  = btot[b];
    int tid  = threadIdx.x;
    if (tid < NPB) hist[tid] = 0;
    __syncthreads();
    // phase A: packed count + weighted degree
    for (int j = tid; j < cnt; j += 256) {
        int2 t = tmp[base + j];
        unsigned dlow = ((unsigned)t.x) >> 24;
        unsigned wfix = (unsigned)(__int_as_float(t.y) * 16384.0f);
        atomicAdd(&hist[dlow], (1u << 24) | wfix);
    }
    __syncthreads();
    int c = 0, incl = 0;
    unsigned pk = 0;
    if (tid < NPB) {
        pk = hist[tid];
        c = (int)(pk >> 24);
        incl = c;
#pragma unroll
        for (int off = 1; off < 64; off <<= 1) {
            int u = __shfl_up(incl, off, 64);
            if ((tid & 63) >= off) incl += u;
        }
        if ((tid & 63) == 63) wsum_[tid >> 6] = incl;
    }
    __syncthreads();
    if (tid < NPB) {
        int woff = (tid >= 64) ? wsum_[0] : 0;
        int excl = woff + incl - c;
        int node = b * NPB + tid;
        float dv = 0.f;
        if (node < n) {
            rowptr[node] = base + excl;
            float wdeg = (float)(pk & 0xFFFFFFu) * (1.0f / 16384.0f);
            dv = rsqrtf(wdeg + 1.0f);
            dinv[node] = dv;
        }
        dvl[tid]  = dv;
        hist[tid] = (unsigned)excl;   // becomes cursor for phase B
    }
    if (b == 0 && tid == 0) rowptr[n] = E;
    __syncthreads();
    // phase B: place edges within bucket
    for (int j = tid; j < cnt; j += 256) {
        int2 t = tmp[base + j];
        unsigned dlow = ((unsigned)t.x) >> 24;
        int srcv = t.x & 0xFFFFFF;
        int lr = (int)atomicAdd(&hist[dlow], 1u);
        csr[base + lr] = make_int2(srcv, t.y);
    }
    // phase C (fused convs): zs[node] = bf16(dinv*z[node]) for this block's nodes
    for (int t = tid; t < NPB * 16; t += 256) {
        int li = t >> 4;
        int node = b * NPB + li;
        if (node < n) {
            int k = t & 15;
            float dv = dvl[li];
            float4 f = ld4(z + (size_t)node * 64 + k * 4);
            zs[(size_t)node * 16 + k] =
                make_uint2(bfr(dv * f.x) | (bfr(dv * f.y) << 16),
                           bfr(dv * f.z) | (bfr(dv * f.w) << 16));
        }
    }
}

// ---- gather-aggregate (F=64, bf16 pre-scaled operand): one wave per dst row ----
// Lane l: eg = l>>3 (8 edge subgroups), fq = l&7 (uint4 = 8 bf16 = 16B/lane).
// 8 edges per wave load instruction; 4-deep unroll = 32 edges in flight.
// out[row] = (BIAS? b : 0) + dv * ( sum_j ew_j * Hp[src_j] + Hp[row] )
// OUTB: write result as bf16 [n][64] (uint4 per lane) instead of f32.
template<bool BIAS, bool OUTB>
__global__ __launch_bounds__(256) void gaggb_kernel(const int* __restrict__ rowptr,
                                                    const int2* __restrict__ csr,
                                                    const float* __restrict__ dinv,
                                                    const uint4* __restrict__ Hp4,
                                                    const float* __restrict__ b,
                                                    void* __restrict__ out, int n) {
    int row  = (blockIdx.x * 256 + threadIdx.x) >> 6;
    int lane = threadIdx.x & 63;
    if (row >= n) return;
    int eg = lane >> 3, fq = lane & 7;
    int beg = rowptr[row], end = rowptr[row + 1];
    float dv = dinv[row];

    float a0 = 0.f, a1 = 0.f, a2 = 0.f, a3 = 0.f;
    float a4 = 0.f, a5 = 0.f, a6 = 0.f, a7 = 0.f;
    float f0, f1, f2, f3, f4, f5, f6, f7;

#define ACCUM(V, W)                                            \
    bf2((V).x, f0, f1); bf2((V).y, f2, f3);                    \
    bf2((V).z, f4, f5); bf2((V).w, f6, f7);                    \
    a0 += (W) * f0; a1 += (W) * f1; a2 += (W) * f2; a3 += (W) * f3; \
    a4 += (W) * f4; a5 += (W) * f5; a6 += (W) * f6; a7 += (W) * f7;

    int j = beg;
    for (; j + 32 <= end; j += 32) {
        int2 m0 = csr[j + eg];
        int2 m1 = csr[j + eg + 8];
        int2 m2 = csr[j + eg + 16];
        int2 m3 = csr[j + eg + 24];
        uint4 v0 = Hp4[(size_t)(unsigned)(m0.x) * 8 + fq];
        uint4 v1 = Hp4[(size_t)(unsigned)(m1.x) * 8 + fq];
        uint4 v2 = Hp4[(size_t)(unsigned)(m2.x) * 8 + fq];
        uint4 v3 = Hp4[(size_t)(unsigned)(m3.x) * 8 + fq];
        float w0 = __int_as_float(m0.y), w1 = __int_as_float(m1.y);
        float w2 = __int_as_float(m2.y), w3 = __int_as_float(m3.y);
        ACCUM(v0, w0) ACCUM(v1, w1) ACCUM(v2, w2) ACCUM(v3, w3)
    }
    for (; j + 8 <= end; j += 8) {
        int2 m0 = csr[j + eg];
        float w0 = __int_as_float(m0.y);
        uint4 v0 = Hp4[(size_t)(unsigned)(m0.x) * 8 + fq];
        ACCUM(v0, w0)
    }
    if (j < end) {
        int idx = j + eg;
        if (idx < end) {
            int2 m0 = csr[idx];
            float w0 = __int_as_float(m0.y);
            uint4 v0 = Hp4[(size_t)(unsigned)(m0.x) * 8 + fq];
            ACCUM(v0, w0)
        }
    }
#undef ACCUM
    // combine the 8 edge subgroups (lane bits 3,4,5)
#pragma unroll
    for (int off = 8; off < 64; off <<= 1) {
        a0 += __shfl_xor(a0, off, 64); a1 += __shfl_xor(a1, off, 64);
        a2 += __shfl_xor(a2, off, 64); a3 += __shfl_xor(a3, off, 64);
        a4 += __shfl_xor(a4, off, 64); a5 += __shfl_xor(a5, off, 64);
        a6 += __shfl_xor(a6, off, 64); a7 += __shfl_xor(a7, off, 64);
    }

    if (eg == 0) {
        uint4 sv = Hp4[(size_t)row * 8 + fq];   // self term (already dinv-scaled)
        float s0, s1, s2, s3, s4, s5, s6, s7;
        bf2(sv.x, s0, s1); bf2(sv.y, s2, s3);
        bf2(sv.z, s4, s5); bf2(sv.w, s6, s7);
        float o0 = dv * (a0 + s0), o1 = dv * (a1 + s1);
        float o2 = dv * (a2 + s2), o3 = dv * (a3 + s3);
        float o4 = dv * (a4 + s4), o5 = dv * (a5 + s5);
        float o6 = dv * (a6 + s6), o7 = dv * (a7 + s7);
        if (BIAS) {
            float4 b0 = ld4(b + fq * 8);
            float4 b1v = ld4(b + fq * 8 + 4);
            o0 += b0.x; o1 += b0.y; o2 += b0.z; o3 += b0.w;
            o4 += b1v.x; o5 += b1v.y; o6 += b1v.z; o7 += b1v.w;
        }
        if (OUTB) {
            uint4 pv = make_uint4(bfr(o0) | (bfr(o1) << 16),
                                  bfr(o2) | (bfr(o3) << 16),
                                  bfr(o4) | (bfr(o5) << 16),
                                  bfr(o6) | (bfr(o7) << 16));
            reinterpret_cast<uint4*>(out)[(size_t)row * 8 + fq] = pv;
        } else {
            float4* op = reinterpret_cast<float4*>((float*)out + (size_t)row * 64 + fq * 8);
            op[0] = make_float4(o0, o1, o2, o3);
            op[1] = make_float4(o4, o5, o6, o7);
        }
    }
}

// ---- fused dense on matrix cores (weights staged in padded LDS) ----
// hs = bf16(dinv * (relu(t1b @ W1 + b1) @ W2)); 64 rows per group, 4 waves x 16.
// Grid-strided; weights converted f32->bf16 during staging (no prep kernel).
// hT slices are wave-local -> no inner barriers needed.
__global__ __launch_bounds__(256) void densemfma_kernel(
        const unsigned short* __restrict__ t1b,   // [n][64] bf16
        const float* __restrict__ W1,             // [64][128] f32
        const float* __restrict__ b1,
        const float* __restrict__ W2,             // [128][64] f32
        const float* __restrict__ dinv,
        unsigned short* __restrict__ hs,          // [n][64] bf16 out
        int n) {
    __shared__ __align__(16) unsigned short W1s[128][68];   // [outcol][k], padded
    __shared__ __align__(16) unsigned short W2s[64][132];   // [outcol][k], padded
    __shared__ float b1s[128];
    __shared__ __align__(16) unsigned short hT[4][16][136];
    for (int i = threadIdx.x; i < 128 * 64; i += 256) {
        int c = i >> 6, k = i & 63;
        W1s[c][k] = (unsigned short)bfr(W1[k * 128 + c]);
    }
    for (int i = threadIdx.x; i < 64 * 128; i += 256) {
        int c = i >> 7, k = i & 127;
        W2s[c][k] = (unsigned short)bfr(W2[k * 64 + c]);
    }
    if (threadIdx.x < 128) b1s[threadIdx.x] = b1[threadIdx.x];
    __syncthreads();

    int wv = threadIdx.x >> 6;
    int l  = threadIdx.x & 63;
    int m  = l & 15, g = l >> 4;
    int ngrp = (n + 63) >> 6;
    for (int grp = blockIdx.x; grp < ngrp; grp += gridDim.x) {
        int R = grp * 64 + wv * 16;
        // ---- stage 1: C1 = t1b @ W1 (16 x 128), bias+relu -> hT tile ----
        short8v a0 = {0,0,0,0,0,0,0,0}, a1 = {0,0,0,0,0,0,0,0};
        int rowA = R + m;
        if (rowA < n) {
            a0 = *reinterpret_cast<const short8v*>(t1b + (size_t)rowA * 64 + 8 * g);
            a1 = *reinterpret_cast<const short8v*>(t1b + (size_t)rowA * 64 + 32 + 8 * g);
        }
#pragma unroll
        for (int ct = 0; ct < 8; ++ct) {
            short8v wb0 = *reinterpret_cast<const short8v*>(&W1s[ct * 16 + m][8 * g]);
            short8v wb1 = *reinterpret_cast<const short8v*>(&W1s[ct * 16 + m][32 + 8 * g]);
            f32x4 c = {0.f, 0.f, 0.f, 0.f};
            c = __builtin_amdgcn_mfma_f32_16x16x32_bf16(a0, wb0, c, 0, 0, 0);
            c = __builtin_amdgcn_mfma_f32_16x16x32_bf16(a1, wb1, c, 0, 0, 0);
            float bb = b1s[ct * 16 + m];
#pragma unroll
            for (int r = 0; r < 4; ++r) {
                float v = fmaxf(c[r] + bb, 0.f);
                hT[wv][4 * g + r][ct * 16 + m] = (unsigned short)bfr(v);
            }
        }
        // ---- stage 2: C2 = hT @ W2 (16 x 64); hT slice is wave-local ----
        f32x4 acc2[4];
#pragma unroll
        for (int ct = 0; ct < 4; ++ct) acc2[ct] = (f32x4){0.f, 0.f, 0.f, 0.f};
#pragma unroll
        for (int kk = 0; kk < 4; ++kk) {
            short8v ha = *reinterpret_cast<const short8v*>(&hT[wv][m][kk * 32 + 8 * g]);
#pragma unroll
            for (int ct = 0; ct < 4; ++ct) {
                short8v wb = *reinterpret_cast<const short8v*>(
                    &W2s[ct * 16 + m][kk * 32 + 8 * g]);
                acc2[ct] = __builtin_amdgcn_mfma_f32_16x16x32_bf16(ha, wb, acc2[ct], 0, 0, 0);
            }
        }
        // ---- epilogue: dinv-scale, bf16, transpose via wave-local hT, store ----
#pragma unroll
        for (int r = 0; r < 4; ++r) {
            int grow = R + 4 * g + r;
            float dv = (grow < n) ? dinv[grow] : 0.f;
#pragma unroll
            for (int ct = 0; ct < 4; ++ct)
                hT[wv][4 * g + r][ct * 16 + m] = (unsigned short)bfr(acc2[ct][r] * dv);
        }
        int growO = R + m;
        if (growO < n) {
            uint4 u0 = *reinterpret_cast<const uint4*>(&hT[wv][m][g * 16]);
            uint4 u1 = *reinterpret_cast<const uint4*>(&hT[wv][m][g * 16 + 8]);
            *reinterpret_cast<uint4*>(hs + (size_t)growO * 64 + g * 16) = u0;
            *reinterpret_cast<uint4*>(hs + (size_t)growO * 64 + g * 16 + 8) = u1;
        }
    }
}

extern "C" void kernel_launch(void* const* d_in, const int* in_sizes, int n_in,
                              void* d_out, int out_size, void* d_ws, size_t ws_size,
                              hipStream_t stream) {
    const float* z  = (const float*)d_in[0];
    const int*   ei = (const int*)d_in[1];
    const float* ea = (const float*)d_in[2];
    const float* W1 = (const float*)d_in[3];
    const float* b1 = (const float*)d_in[4];
    const float* W2 = (const float*)d_in[5];
    const float* b2 = (const float*)d_in[6];
    float* out = (float*)d_out;

    const int n = in_sizes[0] / 64;   // LAT = 64
    const int E = in_sizes[2];
    const int* src = ei;
    const int* dst = ei + E;
    const int NBKT = (n + NPB - 1) / NPB;   // 391 for n=50000 (<=512 required)
    const int G1   = (E + CH - 1) / CH;     // chunk blocks

    float* ws = (float*)d_ws;
    size_t p = 0;
    auto alloc = [&](size_t elems) { size_t o = p; p += (elems + 63) & ~63ull; return o; };
    float* dinv   = ws + alloc(n);
    int*   rowptr = (int*)(ws + alloc((size_t)n + 1));
    int*   btot   = (int*)(ws + alloc(NBKT));
    int2*  csr    = (int2*)(ws + alloc((size_t)E * 2));
    unsigned short* t1b = (unsigned short*)(ws + alloc((size_t)n * 32)); // [n][64] bf16
    uint2* zs     = (uint2*)(ws + alloc((size_t)n * 32));  // bf16 operand / hs
    // region X: tmp + hist (preprocessing only)
    float* X      = ws + alloc((size_t)E * 2 + (size_t)NBKT * G1 + 64);
    int2*  tmp    = (int2*)X;                       // E int2
    int*   hist   = (int*)(X + (size_t)E * 2);      // NBKT*G1 ints
    (void)ws_size;

    // ---- preprocessing: counting sort by dst, zero global atomics ----
    hist_kernel<<<G1, 256, 0, stream>>>(dst, hist, E, G1, NBKT);
    bscan_kernel<<<NBKT, 64, 0, stream>>>(hist, btot, G1);
    scatter_kernel<<<G1, 256, 0, stream>>>(src, dst, ea, hist, btot, tmp, E, G1, NBKT);
    finalize_kernel<<<NBKT, 256, 0, stream>>>(tmp, btot, z, rowptr, dinv,
                                              csr, zs, n, E, NBKT);

    const int gblocks = (n + 3) / 4;
    // ---- layer 1 gather: t1b = bf16(Â z) ----
    gaggb_kernel<false, true><<<gblocks, 256, 0, stream>>>(rowptr, csr, dinv,
                                                           (const uint4*)zs,
                                                           nullptr, t1b, n);
    // ---- fused dense on MFMA: hs = bf16(dinv*(relu(t1b@W1+b1)@W2)) (reuses zs) ----
    densemfma_kernel<<<256, 256, 0, stream>>>(t1b, W1, b1, W2, dinv,
                                              (unsigned short*)zs, n);
    // ---- layer 2 gather: out = Â hs + b2 ----
    gaggb_kernel<true, false><<<gblocks, 256, 0, stream>>>(rowptr, csr, dinv,
                                                           (const uint4*)zs,
                                                           b2, out, n);
}

// Round 17
// 143.691 us; speedup vs baseline: 1.9279x; 1.0223x over previous
//
#include <hip/hip_runtime.h>

// 2-layer GCN, CSR-gather formulation, v17.
//   Â = D^{-1/2}(A+I)D^{-1/2},  out = Â(relu(Â z W1 + b1))W2 + b2
// layer1: t1b = bf16(Â z); dense: hs = bf16(dinv*(relu(t1b@W1+b1)@W2)) on MFMA;
// layer2: out = gather(hs) + b2.
// v6: CSR via counting sort — zero global atomics. v7: bf16 gather operand.
// v9: operand pre-scaled by dinv. v11: convs fused into finalize.
// v13/14: dense on matrix cores. v15/16: 32-edge MLP, 8x16B gather lanes.
// v17: (a) CSR entry 4B: src:u16 (n<2^16) | bf16(ew):u16 — halves CSR stream
// in both gaggs and finalize's write; (b) NPB=64 (NBKT=782) — doubles
// scatter/finalize block parallelism (finalize was ~1.5 blocks/CU).
// R16 established gagg is L2 request-service bound (~1.6M random 128B row
// requests/pass) — instruction-shape levers are exhausted there.

#define NPB 64    // nodes per fine bucket (dst & 63 is the in-bucket id)
#define CH  8192  // edges per chunk block in hist/scatter passes

typedef __attribute__((ext_vector_type(8))) short short8v;
typedef __attribute__((ext_vector_type(4))) float f32x4;

__device__ __forceinline__ float4 ld4(const float* p) {
    return *reinterpret_cast<const float4*>(p);
}

// round-to-nearest-even f32 -> bf16 (as ushort in low bits)
__device__ __forceinline__ unsigned bfr(float f) {
    unsigned u = __float_as_uint(f);
    return (u + 0x7FFFu + ((u >> 16) & 1u)) >> 16;
}
// unpack uint (2 bf16) -> 2 f32
__device__ __forceinline__ void bf2(unsigned v, float& lo, float& hi) {
    lo = __uint_as_float(v << 16);
    hi = __uint_as_float(v & 0xFFFF0000u);
}

// exclusive scan of btot[0..NBKT) into LDS bbs[] (blockDim=256, NBKT<=1024)
__device__ __forceinline__ void scan_btot(const int* __restrict__ btot, int NBKT,
                                          int* bbs, int* wtot) {
    int tid = threadIdx.x;
    int v[4];
    int s = 0;
#pragma unroll
    for (int q = 0; q < 4; ++q) {
        int i = 4 * tid + q;
        v[q] = (i < NBKT) ? btot[i] : 0;
        s += v[q];
    }
    int lane = tid & 63, wid = tid >> 6;
    int incl = s;
#pragma unroll
    for (int off = 1; off < 64; off <<= 1) {
        int u = __shfl_up(incl, off, 64);
        if (lane >= off) incl += u;
    }
    if (lane == 63) wtot[wid] = incl;
    __syncthreads();
    int woff = 0;
#pragma unroll
    for (int w = 0; w < 4; ++w) if (w < wid) woff += wtot[w];
    int ex = woff + incl - s;
#pragma unroll
    for (int q = 0; q < 4; ++q) {
        int i = 4 * tid + q;
        if (i < NBKT) bbs[i] = ex;
        ex += v[q];
    }
    __syncthreads();
}

// ---- K1: coarse histogram per chunk (LDS), bucket-major out: hist[b*G1+g] ----
__global__ __launch_bounds__(256) void hist_kernel(const int* __restrict__ dst,
                                                   int* __restrict__ hist,
                                                   int E, int G1, int NBKT) {
    __shared__ int lh[1024];
    for (int i = threadIdx.x; i < NBKT; i += 256) lh[i] = 0;
    __syncthreads();
    int g = blockIdx.x;
    int beg = g * CH, end = min(beg + CH, E);
    for (int j = beg + (int)threadIdx.x; j < end; j += 256)
        atomicAdd(&lh[dst[j] / NPB], 1);
    __syncthreads();
    for (int i = threadIdx.x; i < NBKT; i += 256) hist[(size_t)i * G1 + g] = lh[i];
}

// ---- K2: per-bucket exclusive scan across chunks (in place); btot[b] = total ----
__global__ __launch_bounds__(64) void bscan_kernel(int* __restrict__ hist,
                                                   int* __restrict__ btot, int G1) {
    int b = blockIdx.x;
    int* row = hist + (size_t)b * G1;
    int lane = threadIdx.x;
    int carry = 0;
    for (int g0 = 0; g0 < G1; g0 += 64) {
        int g = g0 + lane;
        int v = (g < G1) ? row[g] : 0;
        int incl = v;
#pragma unroll
        for (int off = 1; off < 64; off <<= 1) {
            int u = __shfl_up(incl, off, 64);
            if (lane >= off) incl += u;
        }
        if (g < G1) row[g] = carry + incl - v;
        carry += __shfl(incl, 63, 64);
    }
    if (lane == 0) btot[b] = carry;
}

// ---- K3: scatter edges into bucket-grouped tmp via LDS cursors (scan fused) ----
__global__ __launch_bounds__(256) void scatter_kernel(const int* __restrict__ src,
                                                      const int* __restrict__ dst,
                                                      const float* __restrict__ ew,
                                                      const int* __restrict__ hist,
                                                      const int* __restrict__ btot,
                                                      int2* __restrict__ tmp,
                                                      int E, int G1, int NBKT) {
    __shared__ int bbs[1024];
    __shared__ int wtot[4];
    __shared__ int cursor[1024];
    scan_btot(btot, NBKT, bbs, wtot);
    int g = blockIdx.x;
    for (int i = threadIdx.x; i < NBKT; i += 256)
        cursor[i] = bbs[i] + hist[(size_t)i * G1 + g];
    __syncthreads();
    int beg = g * CH, end = min(beg + CH, E);
    for (int j = beg + (int)threadIdx.x; j < end; j += 256) {
        int d = dst[j];
        int b = d / NPB;
        int pos = atomicAdd(&cursor[b], 1);
        tmp[pos] = make_int2(((d & (NPB - 1)) << 24) | src[j], __float_as_int(ew[j]));
    }
}

// ---- K4: per-bucket finalize: rowptr, dinv, final CSR u32 {src, bf16 ew}, zs ----
__global__ __launch_bounds__(256) void finalize_kernel(const int2* __restrict__ tmp,
                                                       const int* __restrict__ btot,
                                                       const float* __restrict__ z,
                                                       int* __restrict__ rowptr,
                                                       float* __restrict__ dinv,
                                                       unsigned* __restrict__ csr,
                                                       uint2* __restrict__ zs,
                                                       int n, int E, int NBKT) {
    __shared__ int bbs[1024];
    __shared__ int wsum_[4];
    __shared__ unsigned int hist[NPB];
    __shared__ float dvl[NPB];
    scan_btot(btot, NBKT, bbs, wsum_);
    int b = blockIdx.x;
    int base = bbs[b];
    int cnt  = btot[b];
    int tid  = threadIdx.x;
    if (tid < NPB) hist[tid] = 0;
    __syncthreads();
    // phase A: packed count (bits 24..31) + weighted degree (2^-14 fix, bits 0..23)
    for (int j = tid; j < cnt; j += 256) {
        int2 t = tmp[base + j];
        unsigned dlow = ((unsigned)t.x) >> 24;
        unsigned wfix = (unsigned)(__int_as_float(t.y) * 16384.0f);
        atomicAdd(&hist[dlow], (1u << 24) | wfix);
    }
    __syncthreads();
    // node-level exclusive scan (NPB=64 -> single wave 0)
    if (tid < NPB) {
        unsigned pk = hist[tid];
        int c = (int)(pk >> 24);
        int incl = c;
#pragma unroll
        for (int off = 1; off < 64; off <<= 1) {
            int u = __shfl_up(incl, off, 64);
            if (tid >= off) incl += u;
        }
        int excl = incl - c;
        int node = b * NPB + tid;
        float dv = 0.f;
        if (node < n) {
            rowptr[node] = base + excl;
            float wdeg = (float)(pk & 0xFFFFFFu) * (1.0f / 16384.0f);
            dv = rsqrtf(wdeg + 1.0f);
            dinv[node] = dv;
        }
        dvl[tid]  = dv;
        hist[tid] = (unsigned)excl;   // becomes cursor for phase B
    }
    if (b == 0 && tid == 0) rowptr[n] = E;
    __syncthreads();
    // phase B: place edges within bucket; csr entry = src | bf16(ew)<<16
    for (int j = tid; j < cnt; j += 256) {
        int2 t = tmp[base + j];
        unsigned dlow = ((unsigned)t.x) >> 24;
        unsigned srcv = (unsigned)(t.x & 0xFFFFFF);
        int lr = (int)atomicAdd(&hist[dlow], 1u);
        csr[base + lr] = srcv | (bfr(__int_as_float(t.y)) << 16);
    }
    // phase C (fused convs): zs[node] = bf16(dinv*z[node]) for this block's nodes
    for (int t = tid; t < NPB * 16; t += 256) {
        int li = t >> 4;
        int node = b * NPB + li;
        if (node < n) {
            int k = t & 15;
            float dv = dvl[li];
            float4 f = ld4(z + (size_t)node * 64 + k * 4);
            zs[(size_t)node * 16 + k] =
                make_uint2(bfr(dv * f.x) | (bfr(dv * f.y) << 16),
                           bfr(dv * f.z) | (bfr(dv * f.w) << 16));
        }
    }
}

// ---- gather-aggregate (F=64, bf16 pre-scaled operand): one wave per dst row ----
// Lane l: eg = l>>3 (8 edge subgroups), fq = l&7 (uint4 = 8 bf16 = 16B/lane).
// csr entry u32: src = lo16, bf16 ew = hi16. 32 edges in flight (4-deep).
// out[row] = (BIAS? b : 0) + dv * ( sum_j ew_j * Hp[src_j] + Hp[row] )
// OUTB: write result as bf16 [n][64] (uint4 per lane) instead of f32.
template<bool BIAS, bool OUTB>
__global__ __launch_bounds__(256) void gaggb_kernel(const int* __restrict__ rowptr,
                                                    const unsigned* __restrict__ csr,
                                                    const float* __restrict__ dinv,
                                                    const uint4* __restrict__ Hp4,
                                                    const float* __restrict__ b,
                                                    void* __restrict__ out, int n) {
    int row  = (blockIdx.x * 256 + threadIdx.x) >> 6;
    int lane = threadIdx.x & 63;
    if (row >= n) return;
    int eg = lane >> 3, fq = lane & 7;
    int beg = rowptr[row], end = rowptr[row + 1];
    float dv = dinv[row];

    float a0 = 0.f, a1 = 0.f, a2 = 0.f, a3 = 0.f;
    float a4 = 0.f, a5 = 0.f, a6 = 0.f, a7 = 0.f;
    float f0, f1, f2, f3, f4, f5, f6, f7;

#define ACCUM(V, W)                                            \
    bf2((V).x, f0, f1); bf2((V).y, f2, f3);                    \
    bf2((V).z, f4, f5); bf2((V).w, f6, f7);                    \
    a0 += (W) * f0; a1 += (W) * f1; a2 += (W) * f2; a3 += (W) * f3; \
    a4 += (W) * f4; a5 += (W) * f5; a6 += (W) * f6; a7 += (W) * f7;

    int j = beg;
    for (; j + 32 <= end; j += 32) {
        unsigned m0 = csr[j + eg];
        unsigned m1 = csr[j + eg + 8];
        unsigned m2 = csr[j + eg + 16];
        unsigned m3 = csr[j + eg + 24];
        uint4 v0 = Hp4[(size_t)(m0 & 0xFFFFu) * 8 + fq];
        uint4 v1 = Hp4[(size_t)(m1 & 0xFFFFu) * 8 + fq];
        uint4 v2 = Hp4[(size_t)(m2 & 0xFFFFu) * 8 + fq];
        uint4 v3 = Hp4[(size_t)(m3 & 0xFFFFu) * 8 + fq];
        float w0 = __uint_as_float(m0 & 0xFFFF0000u);
        float w1 = __uint_as_float(m1 & 0xFFFF0000u);
        float w2 = __uint_as_float(m2 & 0xFFFF0000u);
        float w3 = __uint_as_float(m3 & 0xFFFF0000u);
        ACCUM(v0, w0) ACCUM(v1, w1) ACCUM(v2, w2) ACCUM(v3, w3)
    }
    for (; j + 8 <= end; j += 8) {
        unsigned m0 = csr[j + eg];
        float w0 = __uint_as_float(m0 & 0xFFFF0000u);
        uint4 v0 = Hp4[(size_t)(m0 & 0xFFFFu) * 8 + fq];
        ACCUM(v0, w0)
    }
    if (j < end) {
        int idx = j + eg;
        if (idx < end) {
            unsigned m0 = csr[idx];
            float w0 = __uint_as_float(m0 & 0xFFFF0000u);
            uint4 v0 = Hp4[(size_t)(m0 & 0xFFFFu) * 8 + fq];
            ACCUM(v0, w0)
        }
    }
#undef ACCUM
    // combine the 8 edge subgroups (lane bits 3,4,5)
#pragma unroll
    for (int off = 8; off < 64; off <<= 1) {
        a0 += __shfl_xor(a0, off, 64); a1 += __shfl_xor(a1, off, 64);
        a2 += __shfl_xor(a2, off, 64); a3 += __shfl_xor(a3, off, 64);
        a4 += __shfl_xor(a4, off, 64); a5 += __shfl_xor(a5, off, 64);
        a6 += __shfl_xor(a6, off, 64); a7 += __shfl_xor(a7, off, 64);
    }

    if (eg == 0) {
        uint4 sv = Hp4[(size_t)row * 8 + fq];   // self term (already dinv-scaled)
        float s0, s1, s2, s3, s4, s5, s6, s7;
        bf2(sv.x, s0, s1); bf2(sv.y, s2, s3);
        bf2(sv.z, s4, s5); bf2(sv.w, s6, s7);
        float o0 = dv * (a0 + s0), o1 = dv * (a1 + s1);
        float o2 = dv * (a2 + s2), o3 = dv * (a3 + s3);
        float o4 = dv * (a4 + s4), o5 = dv * (a5 + s5);
        float o6 = dv * (a6 + s6), o7 = dv * (a7 + s7);
        if (BIAS) {
            float4 b0 = ld4(b + fq * 8);
            float4 b1v = ld4(b + fq * 8 + 4);
            o0 += b0.x; o1 += b0.y; o2 += b0.z; o3 += b0.w;
            o4 += b1v.x; o5 += b1v.y; o6 += b1v.z; o7 += b1v.w;
        }
        if (OUTB) {
            uint4 pv = make_uint4(bfr(o0) | (bfr(o1) << 16),
                                  bfr(o2) | (bfr(o3) << 16),
                                  bfr(o4) | (bfr(o5) << 16),
                                  bfr(o6) | (bfr(o7) << 16));
            reinterpret_cast<uint4*>(out)[(size_t)row * 8 + fq] = pv;
        } else {
            float4* op = reinterpret_cast<float4*>((float*)out + (size_t)row * 64 + fq * 8);
            op[0] = make_float4(o0, o1, o2, o3);
            op[1] = make_float4(o4, o5, o6, o7);
        }
    }
}

// ---- fused dense on matrix cores (weights staged in padded LDS) ----
// hs = bf16(dinv * (relu(t1b @ W1 + b1) @ W2)); 64 rows per group, 4 waves x 16.
// Grid-strided; weights converted f32->bf16 during staging (no prep kernel).
// hT slices are wave-local -> no inner barriers needed.
__global__ __launch_bounds__(256) void densemfma_kernel(
        const unsigned short* __restrict__ t1b,   // [n][64] bf16
        const float* __restrict__ W1,             // [64][128] f32
        const float* __restrict__ b1,
        const float* __restrict__ W2,             // [128][64] f32
        const float* __restrict__ dinv,
        unsigned short* __restrict__ hs,          // [n][64] bf16 out
        int n) {
    __shared__ __align__(16) unsigned short W1s[128][68];   // [outcol][k], padded
    __shared__ __align__(16) unsigned short W2s[64][132];   // [outcol][k], padded
    __shared__ float b1s[128];
    __shared__ __align__(16) unsigned short hT[4][16][136];
    for (int i = threadIdx.x; i < 128 * 64; i += 256) {
        int c = i >> 6, k = i & 63;
        W1s[c][k] = (unsigned short)bfr(W1[k * 128 + c]);
    }
    for (int i = threadIdx.x; i < 64 * 128; i += 256) {
        int c = i >> 7, k = i & 127;
        W2s[c][k] = (unsigned short)bfr(W2[k * 64 + c]);
    }
    if (threadIdx.x < 128) b1s[threadIdx.x] = b1[threadIdx.x];
    __syncthreads();

    int wv = threadIdx.x >> 6;
    int l  = threadIdx.x & 63;
    int m  = l & 15, g = l >> 4;
    int ngrp = (n + 63) >> 6;
    for (int grp = blockIdx.x; grp < ngrp; grp += gridDim.x) {
        int R = grp * 64 + wv * 16;
        // ---- stage 1: C1 = t1b @ W1 (16 x 128), bias+relu -> hT tile ----
        short8v a0 = {0,0,0,0,0,0,0,0}, a1 = {0,0,0,0,0,0,0,0};
        int rowA = R + m;
        if (rowA < n) {
            a0 = *reinterpret_cast<const short8v*>(t1b + (size_t)rowA * 64 + 8 * g);
            a1 = *reinterpret_cast<const short8v*>(t1b + (size_t)rowA * 64 + 32 + 8 * g);
        }
#pragma unroll
        for (int ct = 0; ct < 8; ++ct) {
            short8v wb0 = *reinterpret_cast<const short8v*>(&W1s[ct * 16 + m][8 * g]);
            short8v wb1 = *reinterpret_cast<const short8v*>(&W1s[ct * 16 + m][32 + 8 * g]);
            f32x4 c = {0.f, 0.f, 0.f, 0.f};
            c = __builtin_amdgcn_mfma_f32_16x16x32_bf16(a0, wb0, c, 0, 0, 0);
            c = __builtin_amdgcn_mfma_f32_16x16x32_bf16(a1, wb1, c, 0, 0, 0);
            float bb = b1s[ct * 16 + m];
#pragma unroll
            for (int r = 0; r < 4; ++r) {
                float v = fmaxf(c[r] + bb, 0.f);
                hT[wv][4 * g + r][ct * 16 + m] = (unsigned short)bfr(v);
            }
        }
        // ---- stage 2: C2 = hT @ W2 (16 x 64); hT slice is wave-local ----
        f32x4 acc2[4];
#pragma unroll
        for (int ct = 0; ct < 4; ++ct) acc2[ct] = (f32x4){0.f, 0.f, 0.f, 0.f};
#pragma unroll
        for (int kk = 0; kk < 4; ++kk) {
            short8v ha = *reinterpret_cast<const short8v*>(&hT[wv][m][kk * 32 + 8 * g]);
#pragma unroll
            for (int ct = 0; ct < 4; ++ct) {
                short8v wb = *reinterpret_cast<const short8v*>(
                    &W2s[ct * 16 + m][kk * 32 + 8 * g]);
                acc2[ct] = __builtin_amdgcn_mfma_f32_16x16x32_bf16(ha, wb, acc2[ct], 0, 0, 0);
            }
        }
        // ---- epilogue: dinv-scale, bf16, transpose via wave-local hT, store ----
#pragma unroll
        for (int r = 0; r < 4; ++r) {
            int grow = R + 4 * g + r;
            float dv = (grow < n) ? dinv[grow] : 0.f;
#pragma unroll
            for (int ct = 0; ct < 4; ++ct)
                hT[wv][4 * g + r][ct * 16 + m] = (unsigned short)bfr(acc2[ct][r] * dv);
        }
        int growO = R + m;
        if (growO < n) {
            uint4 u0 = *reinterpret_cast<const uint4*>(&hT[wv][m][g * 16]);
            uint4 u1 = *reinterpret_cast<const uint4*>(&hT[wv][m][g * 16 + 8]);
            *reinterpret_cast<uint4*>(hs + (size_t)growO * 64 + g * 16) = u0;
            *reinterpret_cast<uint4*>(hs + (size_t)growO * 64 + g * 16 + 8) = u1;
        }
    }
}

extern "C" void kernel_launch(void* const* d_in, const int* in_sizes, int n_in,
                              void* d_out, int out_size, void* d_ws, size_t ws_size,
                              hipStream_t stream) {
    const float* z  = (const float*)d_in[0];
    const int*   ei = (const int*)d_in[1];
    const float* ea = (const float*)d_in[2];
    const float* W1 = (const float*)d_in[3];
    const float* b1 = (const float*)d_in[4];
    const float* W2 = (const float*)d_in[5];
    const float* b2 = (const float*)d_in[6];
    float* out = (float*)d_out;

    const int n = in_sizes[0] / 64;   // LAT = 64
    const int E = in_sizes[2];
    const int* src = ei;
    const int* dst = ei + E;
    const int NBKT = (n + NPB - 1) / NPB;   // 782 for n=50000 (<=1024 required)
    const int G1   = (E + CH - 1) / CH;     // chunk blocks

    float* ws = (float*)d_ws;
    size_t p = 0;
    auto alloc = [&](size_t elems) { size_t o = p; p += (elems + 63) & ~63ull; return o; };
    float*    dinv   = ws + alloc(n);
    int*      rowptr = (int*)(ws + alloc((size_t)n + 1));
    int*      btot   = (int*)(ws + alloc(NBKT));
    unsigned* csr    = (unsigned*)(ws + alloc(E));        // u32 {src:u16, bf16 ew}
    unsigned short* t1b = (unsigned short*)(ws + alloc((size_t)n * 32)); // [n][64] bf16
    uint2*    zs     = (uint2*)(ws + alloc((size_t)n * 32));  // bf16 operand / hs
    // region X: tmp + hist (preprocessing only)
    float*    X      = ws + alloc((size_t)E * 2 + (size_t)NBKT * G1 + 64);
    int2*     tmp    = (int2*)X;                       // E int2
    int*      hist   = (int*)(X + (size_t)E * 2);      // NBKT*G1 ints
    (void)ws_size;

    // ---- preprocessing: counting sort by dst, zero global atomics ----
    hist_kernel<<<G1, 256, 0, stream>>>(dst, hist, E, G1, NBKT);
    bscan_kernel<<<NBKT, 64, 0, stream>>>(hist, btot, G1);
    scatter_kernel<<<G1, 256, 0, stream>>>(src, dst, ea, hist, btot, tmp, E, G1, NBKT);
    finalize_kernel<<<NBKT, 256, 0, stream>>>(tmp, btot, z, rowptr, dinv,
                                              csr, zs, n, E, NBKT);

    const int gblocks = (n + 3) / 4;
    // ---- layer 1 gather: t1b = bf16(Â z) ----
    gaggb_kernel<false, true><<<gblocks, 256, 0, stream>>>(rowptr, csr, dinv,
                                                           (const uint4*)zs,
                                                           nullptr, t1b, n);
    // ---- fused dense on MFMA: hs = bf16(dinv*(relu(t1b@W1+b1)@W2)) (reuses zs) ----
    densemfma_kernel<<<256, 256, 0, stream>>>(t1b, W1, b1, W2, dinv,
                                              (unsigned short*)zs, n);
    // ---- layer 2 gather: out = Â hs + b2 ----
    gaggb_kernel<true, false><<<gblocks, 256, 0, stream>>>(rowptr, csr, dinv,
                                                           (const uint4*)zs,
                                                           b2, out, n);
}